// Round 5
// baseline (577.314 us; speedup 1.0000x reference)
//
#include <hip/hip_runtime.h>
#include <hip/hip_fp16.h>
#include <hip/hip_cooperative_groups.h>

namespace cg = cooperative_groups;

#define FEAT 32
#define BIN_NODES 128
#define BIN_SHIFT 7
#define TILE_EDGES 8192   // edges per build block
#define BWAVES 16         // waves per build block (1024 threads)
#define SRC_BITS 20
#define SRC_MASK 0xFFFFF
#define STAGE_CAP 6144    // LDS staging cap for a bin's packed edges (24 KB)

__device__ __forceinline__ int load_idx(const void* raw, int f, long long i) {
    return f ? (int)((const long long*)raw)[i] : ((const int*)raw)[i];
}

// logical L = b*nblk + k (bin-major) <-> physical p = k*nb + b
__device__ __forceinline__ int l2p(int L, int nb, int nblk) {
    int b = L / nblk;
    int k = L - b * nblk;
    return k * nb + b;
}

// ONE cooperative kernel for the whole CSR build + fused layer-1 transform.
// Phases (grid.sync between): A) tile edges -> REGISTERS + per-(tile,bin)
// LDS histogram -> mat; S1) distributed block scan (784 virtual 256-blocks);
// S2) block-0 scan of block sums; C) scatter packed recs from the registers
// (edge list read exactly ONCE); D) per-bin degree-sort (4 bins/block) with
// LDS staging + fused h1 = fp16(dis * (x@W1)).
// 196 blocks x 1024 threads, ~49 KB dynamic LDS -> 1 block/CU, all resident.
__global__ __launch_bounds__(1024, 4)
void build_kernel(const void* __restrict__ raw, int* __restrict__ mat,
                  int* __restrict__ bsum, int* __restrict__ packed,
                  float* __restrict__ dis, int* __restrict__ row_start,
                  int* __restrict__ recs, const float* __restrict__ x,
                  const float* __restrict__ W1, __half* __restrict__ h1,
                  int e, int n, int nb, int nblk, int nbks, int M) {
    extern __shared__ int lds[];   // (BWAVES*nb + 1) ints
    cg::grid_group grid = cg::this_grid();
    const int t = threadIdx.x, blk = blockIdx.x;
    const int w = t >> 6;

    // ---------------- phase A: edges -> regs, histogram ----------------
    const int nzoff = BWAVES * nb;
    for (int i = t; i < BWAVES * nb; i += 1024) lds[i] = 0;
    if (t == 0) lds[nzoff] = 0;
    __syncthreads();
    if (((const int*)raw)[2 * t + 1] != 0) lds[nzoff] = 1;   // benign race
    __syncthreads();
    const int f = (lds[nzoff] == 0) ? 1 : 0;
    if (blk == 0 && t == 0) row_start[n] = e;   // sentinel

    long long base = (long long)blk * TILE_EDGES;
    int cnt_e = (int)min((long long)TILE_EDGES, (long long)e - base);
    int sreg[8], dreg[8];
    int* hw = lds + w * nb;
#pragma unroll
    for (int k = 0; k < 8; ++k) {
        int i = t + k * 1024;
        if (i < cnt_e) {
            sreg[k] = load_idx(raw, f, base + i);
            dreg[k] = load_idx(raw, f, (long long)e + base + i);
            atomicAdd(&hw[dreg[k] >> BIN_SHIFT], 1);
        } else {
            dreg[k] = -1;
        }
    }
    __syncthreads();
    for (int b2 = t; b2 < nb; b2 += 1024) {
        int s = 0;
#pragma unroll
        for (int w2 = 0; w2 < BWAVES; ++w2) s += lds[w2 * nb + b2];
        mat[blk * nb + b2] = s;
    }
    __threadfence();
    grid.sync();

    // ---------------- phase S1: distributed scan (4 virtual blocks) -----
    {
        int v = blk * 4 + (t >> 8);
        int lt = t & 255;
        int* sd = lds + (t >> 8) * 256;
        int L = v * 256 + lt;
        int p = 0, val = 0;
        if (L < M) { p = l2p(L, nb, nblk); val = mat[p]; }
        sd[lt] = val;
        __syncthreads();
        for (int off = 1; off < 256; off <<= 1) {
            int add = (lt >= off) ? sd[lt - off] : 0;
            __syncthreads();
            sd[lt] += add;
            __syncthreads();
        }
        if (L < M) mat[p] = sd[lt] - val;   // exclusive within scan-block
        if (lt == 255 && v < nbks) bsum[v] = sd[lt];
    }
    __threadfence();
    grid.sync();

    // ---------------- phase S2: scan of block sums (block 0) ------------
    if (blk == 0) {
        int v2 = (t < nbks) ? bsum[t] : 0;
        lds[t] = v2;
        __syncthreads();
        for (int off = 1; off < 1024; off <<= 1) {
            int add = (t >= off) ? lds[t - off] : 0;
            __syncthreads();
            lds[t] += add;
            __syncthreads();
        }
        if (t < nbks) bsum[t] = lds[t] - v2;
    }
    __threadfence();
    grid.sync();

    // ---------------- phase C: scatter packed from regs -----------------
    {
        int* cur = lds;   // nb ints
        for (int i = t; i < nb; i += 1024)
            cur[i] = mat[blk * nb + i] + bsum[(i * nblk + blk) >> 8];
        __syncthreads();
#pragma unroll
        for (int k = 0; k < 8; ++k) {
            int d = dreg[k];
            if (d >= 0) {
                int pos = atomicAdd(&cur[d >> BIN_SHIFT], 1);
                packed[pos] = sreg[k] | ((d & (BIN_NODES - 1)) << SRC_BITS);
            }
        }
    }
    __threadfence();
    grid.sync();

    // ---------------- phase D: degsort + fused mm1, 4 bins/block --------
    // LDS layout (ints): cnt[0,2048) wcur[2048,4096) exc[4096,4224)
    // sdis[4224,4352) W1l[4352,5376) stage[5376,11520)
    int* cntL  = lds;
    int* wcurL = lds + 2048;
    int* excL  = lds + 4096;
    float* sdisL = (float*)(lds + 4224);
    float* W1l   = (float*)(lds + 4352);
    int* stageL  = lds + 5376;
    W1l[t] = W1[t];   // 1024 threads, 1024 elems; synced inside loop before use

    for (int b = blk; b < nb; b += nblk) {
        __syncthreads();   // protect LDS reuse across iterations
        for (int i = t; i < BWAVES * BIN_NODES; i += 1024) cntL[i] = 0;
        __syncthreads();
        int start = mat[b] + bsum[(b * nblk) >> 8];
        int end = (b + 1 < nb) ? (mat[b + 1] + bsum[((b + 1) * nblk) >> 8]) : e;
        int m = end - start;
        if (m <= STAGE_CAP) {
            for (int i = t; i < m; i += 1024) {
                int rec = packed[start + i];
                stageL[i] = rec;
                atomicAdd(&cntL[w * BIN_NODES + (rec >> SRC_BITS)], 1);
            }
        } else {
            for (int i = start + t; i < end; i += 1024)
                atomicAdd(&cntL[w * BIN_NODES + (packed[i] >> SRC_BITS)], 1);
        }
        __syncthreads();
        if (t < BIN_NODES) {
            int s = 0;
#pragma unroll
            for (int w2 = 0; w2 < BWAVES; ++w2) s += cntL[w2 * BIN_NODES + t];
            excL[t] = s;
        }
        __syncthreads();
        for (int off = 1; off < BIN_NODES; off <<= 1) {
            int v = 0;
            if (t < BIN_NODES && t >= off) v = excL[t - off];
            __syncthreads();
            if (t < BIN_NODES) excL[t] += v;
            __syncthreads();
        }
        if (t < BIN_NODES) {
            int tot = 0;
#pragma unroll
            for (int w2 = 0; w2 < BWAVES; ++w2) tot += cntL[w2 * BIN_NODES + t];
            int rs = start + excL[t] - tot;   // inclusive -> exclusive
            int run = rs;
#pragma unroll
            for (int w2 = 0; w2 < BWAVES; ++w2) {
                wcurL[w2 * BIN_NODES + t] = run;
                run += cntL[w2 * BIN_NODES + t];
            }
            float dv = rsqrtf((float)tot + 1.0f);
            sdisL[t] = dv;
            int node = b * BIN_NODES + t;
            if (node < n) { dis[node] = dv; row_start[node] = rs; }
        }
        __syncthreads();
        if (m <= STAGE_CAP) {
            for (int i = t; i < m; i += 1024) {
                int rec = stageL[i];
                int pos = atomicAdd(&wcurL[w * BIN_NODES + (rec >> SRC_BITS)], 1);
                recs[pos] = rec & SRC_MASK;
            }
        } else {
            for (int i = start + t; i < end; i += 1024) {
                int rec = packed[i];
                int pos = atomicAdd(&wcurL[w * BIN_NODES + (rec >> SRC_BITS)], 1);
                recs[pos] = rec & SRC_MASK;
            }
        }
        // fused mm1: 8 threads/node; thread holds one float4 of x-row.
        {
            int ln = b * BIN_NODES + (t >> 3);
            if (ln < n) {
                int q = t & 7;
                float4 xv = ((const float4*)x)[(size_t)ln * 8 + q];
                float xr[4] = {xv.x, xv.y, xv.z, xv.w};
                float o[4] = {0.f, 0.f, 0.f, 0.f};
#pragma unroll
                for (int k = 0; k < FEAT; ++k) {
                    float xk = __shfl(xr[k & 3], k >> 2, 8);
#pragma unroll
                    for (int c = 0; c < 4; ++c)
                        o[c] = fmaf(xk, W1l[k * FEAT + q * 4 + c], o[c]);
                }
                float dn = sdisL[t >> 3];
                __half2* hp = (__half2*)&h1[(size_t)ln * FEAT + q * 4];
                hp[0] = __halves2half2(__float2half(dn * o[0]), __float2half(dn * o[1]));
                hp[1] = __halves2half2(__float2half(dn * o[2]), __float2half(dn * o[3]));
            }
        }
    }
}

// Layer-1 pull FUSED with layer-2 transform, 8 lanes/node (2 slots x 4
// feature-quads): window covers 16 records (~deg), so all 8 load slots are
// useful and 8 gathers/lane are in flight. 1-level slot butterfly; mm2 as
// distributed 8x16 register blocks + 2-level fb butterfly. W2 in LDS with
// +1 row padding (stride 33) -> worst 2-way bank aliasing (free).
__global__ __launch_bounds__(256, 8)
void pull_mm_kernel(const int* __restrict__ recs, const int* __restrict__ row_start,
                    const __half* __restrict__ h, const float* __restrict__ dis,
                    const float* __restrict__ bias, const float* __restrict__ W2,
                    __half* __restrict__ h2, int n) {
    __shared__ float Wl[FEAT * 33];
    int t = threadIdx.x;
    for (int i = t; i < FEAT * FEAT; i += 256) {
        int k = i >> 5, j = i & 31;
        Wl[k * 33 + j] = W2[i];
    }
    __syncthreads();
    int node = blockIdx.x * 32 + (t >> 3);
    if (node >= n) return;
    int g = t & 7;
    int sub = g >> 2;   // record slot 0..1
    int fb = g & 3;     // float4 feature block (8 halves)
    int start = row_start[node];
    int deg = row_start[node + 1] - start;
    const float4* h4 = (const float4*)h;  // 8 halves per float4, 4 per row
    float s0 = 0, s1 = 0, s2 = 0, s3 = 0, s4 = 0, s5 = 0, s6 = 0, s7 = 0;
    for (int r0 = 0; r0 < deg; r0 += 16) {
#pragma unroll
        for (int w = 0; w < 8; ++w) {
            int r = r0 + w * 2 + sub;
            if (r < deg) {
                int s = recs[start + r];
                float4 v = h4[(size_t)s * 4 + fb];
                const __half2* hp = (const __half2*)&v;
                float2 a = __half22float2(hp[0]);
                float2 b = __half22float2(hp[1]);
                float2 c = __half22float2(hp[2]);
                float2 d = __half22float2(hp[3]);
                s0 += a.x; s1 += a.y; s2 += b.x; s3 += b.y;
                s4 += c.x; s5 += c.y; s6 += d.x; s7 += d.y;
            }
        }
    }
    // 1-level butterfly over slots (xor 4) -> both sub lanes hold fb totals
    s0 += __shfl_xor(s0, 4, 64); s1 += __shfl_xor(s1, 4, 64);
    s2 += __shfl_xor(s2, 4, 64); s3 += __shfl_xor(s3, 4, 64);
    s4 += __shfl_xor(s4, 4, 64); s5 += __shfl_xor(s5, 4, 64);
    s6 += __shfl_xor(s6, 4, 64); s7 += __shfl_xor(s7, 4, 64);
    float dn = dis[node];
    float4 hv = h4[(size_t)node * 4 + fb];   // self-loop: + h~[node]
    const __half2* hp = (const __half2*)&hv;
    float2 a = __half22float2(hp[0]);
    float2 b = __half22float2(hp[1]);
    float2 c = __half22float2(hp[2]);
    float2 d = __half22float2(hp[3]);
    const float4* bv4 = (const float4*)bias;
    float4 b0 = bv4[fb * 2], b1 = bv4[fb * 2 + 1];
    float o[8];
    o[0] = fmaxf(fmaf(dn, s0 + a.x, b0.x), 0.0f);
    o[1] = fmaxf(fmaf(dn, s1 + a.y, b0.y), 0.0f);
    o[2] = fmaxf(fmaf(dn, s2 + b.x, b0.z), 0.0f);
    o[3] = fmaxf(fmaf(dn, s3 + b.y, b0.w), 0.0f);
    o[4] = fmaxf(fmaf(dn, s4 + c.x, b1.x), 0.0f);
    o[5] = fmaxf(fmaf(dn, s5 + c.y, b1.y), 0.0f);
    o[6] = fmaxf(fmaf(dn, s6 + d.x, b1.z), 0.0f);
    o[7] = fmaxf(fmaf(dn, s7 + d.y, b1.w), 0.0f);
    // mm2: lane (sub,fb) computes partials for out features j in
    // [sub*16, sub*16+16) over its k in [8fb, 8fb+8), from regs + LDS.
    float part[16];
#pragma unroll
    for (int j = 0; j < 16; ++j) part[j] = 0.f;
    const float* wrow = &Wl[(fb * 8) * 33 + sub * 16];
#pragma unroll
    for (int cc = 0; cc < 8; ++cc) {
#pragma unroll
        for (int j = 0; j < 16; ++j)
            part[j] = fmaf(o[cc], wrow[cc * 33 + j], part[j]);
    }
    // 2-level butterfly over fb (xor 1, 2) -> full k-sum on fb==0 lanes
#pragma unroll
    for (int m = 1; m <= 2; m <<= 1) {
#pragma unroll
        for (int j = 0; j < 16; ++j) part[j] += __shfl_xor(part[j], m, 64);
    }
    if (fb == 0) {
        float4 pk0, pk1;
#pragma unroll
        for (int q = 0; q < 4; ++q) {
            ((__half2*)&pk0)[q] = __halves2half2(__float2half(dn * part[2 * q]),
                                                 __float2half(dn * part[2 * q + 1]));
            ((__half2*)&pk1)[q] = __halves2half2(__float2half(dn * part[8 + 2 * q]),
                                                 __float2half(dn * part[8 + 2 * q + 1]));
        }
        ((float4*)h2)[(size_t)node * 4 + sub * 2]     = pk0;  // feats sub*16..+7
        ((float4*)h2)[(size_t)node * 4 + sub * 2 + 1] = pk1;  // feats sub*16+8..+15
    }
}

// Final pull, 8 lanes/node: out[d] = relu( dis[d]*(sum h~[s] + h~[d]) + b ).
__global__ __launch_bounds__(256, 8)
void pull_kernel(const int* __restrict__ recs, const int* __restrict__ row_start,
                 const __half* __restrict__ h, const float* __restrict__ dis,
                 const float* __restrict__ bias, float* __restrict__ out, int n) {
    int t = threadIdx.x;
    int node = blockIdx.x * 32 + (t >> 3);
    if (node >= n) return;
    int g = t & 7;
    int sub = g >> 2;   // record slot 0..1
    int fb = g & 3;     // float4 feature block (8 halves)
    int start = row_start[node];
    int deg = row_start[node + 1] - start;
    const float4* h4 = (const float4*)h;  // 8 halves per float4, 4 per row
    float s0 = 0, s1 = 0, s2 = 0, s3 = 0, s4 = 0, s5 = 0, s6 = 0, s7 = 0;
    for (int r0 = 0; r0 < deg; r0 += 16) {
#pragma unroll
        for (int w = 0; w < 8; ++w) {
            int r = r0 + w * 2 + sub;
            if (r < deg) {
                int s = recs[start + r];
                float4 v = h4[(size_t)s * 4 + fb];
                const __half2* hp = (const __half2*)&v;
                float2 a = __half22float2(hp[0]);
                float2 b = __half22float2(hp[1]);
                float2 c = __half22float2(hp[2]);
                float2 d = __half22float2(hp[3]);
                s0 += a.x; s1 += a.y; s2 += b.x; s3 += b.y;
                s4 += c.x; s5 += c.y; s6 += d.x; s7 += d.y;
            }
        }
    }
    s0 += __shfl_xor(s0, 4, 64); s1 += __shfl_xor(s1, 4, 64);
    s2 += __shfl_xor(s2, 4, 64); s3 += __shfl_xor(s3, 4, 64);
    s4 += __shfl_xor(s4, 4, 64); s5 += __shfl_xor(s5, 4, 64);
    s6 += __shfl_xor(s6, 4, 64); s7 += __shfl_xor(s7, 4, 64);
    if (sub == 0) {
        float dn = dis[node];
        float4 hv = h4[(size_t)node * 4 + fb];   // self-loop: + h~[node]
        const __half2* hp = (const __half2*)&hv;
        float2 a = __half22float2(hp[0]);
        float2 b = __half22float2(hp[1]);
        float2 c = __half22float2(hp[2]);
        float2 d = __half22float2(hp[3]);
        const float4* bv4 = (const float4*)bias;
        float4 b0 = bv4[fb * 2], b1 = bv4[fb * 2 + 1];
        float4 o0, o1;
        o0.x = fmaxf(fmaf(dn, s0 + a.x, b0.x), 0.0f);
        o0.y = fmaxf(fmaf(dn, s1 + a.y, b0.y), 0.0f);
        o0.z = fmaxf(fmaf(dn, s2 + b.x, b0.z), 0.0f);
        o0.w = fmaxf(fmaf(dn, s3 + b.y, b0.w), 0.0f);
        o1.x = fmaxf(fmaf(dn, s4 + c.x, b1.x), 0.0f);
        o1.y = fmaxf(fmaf(dn, s5 + c.y, b1.y), 0.0f);
        o1.z = fmaxf(fmaf(dn, s6 + d.x, b1.z), 0.0f);
        o1.w = fmaxf(fmaf(dn, s7 + d.y, b1.w), 0.0f);
        ((float4*)out)[(size_t)node * 8 + fb * 2] = o0;
        ((float4*)out)[(size_t)node * 8 + fb * 2 + 1] = o1;
    }
}

extern "C" void kernel_launch(void* const* d_in, const int* in_sizes, int n_in,
                              void* d_out, int out_size, void* d_ws, size_t ws_size,
                              hipStream_t stream) {
    const float* x = (const float*)d_in[0];
    const void* eidx_raw = d_in[1];
    const float* W1 = (const float*)d_in[2];
    const float* b1 = (const float*)d_in[3];
    const float* W2 = (const float*)d_in[4];
    const float* b2 = (const float*)d_in[5];
    float* out = (float*)d_out;

    int n = in_sizes[0] / FEAT;                    // 100000
    int e = in_sizes[1] / 2;                       // 1600000
    int nb = (n + BIN_NODES - 1) / BIN_NODES;      // 782
    int nblk = (e + TILE_EDGES - 1) / TILE_EDGES;  // 196
    int M = nb * nblk;                             // 153k
    int nbks = (M + 255) / 256;                    // 599 <= 1024

    // Workspace (256B-aligned). `packed` aliases `h2` (packed dead after
    // build_kernel; h2 first written by pull_mm; both exactly e*4 bytes).
    char* ws = (char*)d_ws;
    size_t off = 0;
    auto alloc = [&](size_t bytes) { char* p = ws + off; off = (off + bytes + 255) & ~(size_t)255; return p; };
    int*    mat       = (int*)   alloc((size_t)M * 4);
    int*    bsum      = (int*)   alloc((size_t)nbks * 4);
    float*  dis       = (float*) alloc((size_t)n * 4);
    int*    row_start = (int*)   alloc((size_t)(n + 1) * 4);
    int*    recs      = (int*)   alloc((size_t)e * 4);
    __half* h1        = (__half*)alloc((size_t)n * FEAT * 2);
    __half* h2        = (__half*)alloc((size_t)(n * FEAT * 2 > e * 4 ? (size_t)n * FEAT * 2 : (size_t)e * 4));
    int*    packed    = (int*)h2;

    const size_t ldsB = (size_t)(BWAVES * nb + 1) * 4;   // ~49 KB
    const int gNode = (n + 31) / 32;

    // Fused cooperative CSR build + mm1 (196 blocks -> 1/CU, all resident)
    void* args[] = {(void*)&eidx_raw, (void*)&mat, (void*)&bsum, (void*)&packed,
                    (void*)&dis, (void*)&row_start, (void*)&recs, (void*)&x,
                    (void*)&W1, (void*)&h1, (void*)&e, (void*)&n, (void*)&nb,
                    (void*)&nblk, (void*)&nbks, (void*)&M};
    hipLaunchCooperativeKernel((void*)build_kernel, dim3(nblk), dim3(1024),
                               args, (unsigned int)ldsB, stream);

    // Layer-1 aggregate + fused layer-2 transform (-> h2)
    pull_mm_kernel<<<gNode, 256, 0, stream>>>(recs, row_start, h1, dis, b1, W2, h2, n);
    // Layer-2 aggregate + bias + final relu
    pull_kernel<<<gNode, 256, 0, stream>>>(recs, row_start, h2, dis, b2, out, n);
}

// Round 6
// 187.406 us; speedup vs baseline: 3.0805x; 3.0805x over previous
//
#include <hip/hip_runtime.h>
#include <hip/hip_fp16.h>

#define FEAT 32
#define BIN_NODES 128
#define BIN_SHIFT 7
#define TILE_EDGES 8192   // edges per build block
#define BWAVES 16         // waves per build block (1024 threads)
#define SRC_BITS 20
#define SRC_MASK 0xFFFFF
#define STAGE_CAP 6144    // LDS staging cap for a bin's packed edges (24 KB)

// Block-local int64-vs-int32 detection: odd 32-bit words of an int64 index
// array (values < 2^31) are all zero; for int32 they are random node ids.
__device__ __forceinline__ int block_detect_int64(const int* __restrict__ raw32, int* nz) {
    if (threadIdx.x == 0) *nz = 0;
    __syncthreads();
    if (raw32[2 * threadIdx.x + 1] != 0) *nz = 1;
    __syncthreads();
    return (*nz == 0) ? 1 : 0;
}

__device__ __forceinline__ int load_idx(const void* raw, int f, long long i) {
    return f ? (int)((const long long*)raw)[i] : ((const int*)raw)[i];
}

// Phase A: per-(tile,bin) histogram, 16 wave-private copies (1024 threads).
// Writes per-tile counts to mat[blk*nb+b] AND accumulates global per-bin
// totals (replaces the old 153K-element scan input).
__global__ __launch_bounds__(1024)
void binA_kernel(const void* __restrict__ raw, int* __restrict__ mat,
                 int* __restrict__ bin_tot, int e, int nb) {
    extern __shared__ int hist[];  // BWAVES*nb + 1
    int t = threadIdx.x;
    for (int i = t; i < BWAVES * nb; i += 1024) hist[i] = 0;
    int f = block_detect_int64((const int*)raw, &hist[BWAVES * nb]);
    int w = t >> 6, lane = t & 63;
    long long base = (long long)blockIdx.x * TILE_EDGES;
    int cnt = (int)min((long long)TILE_EDGES, (long long)e - base);
    int* hw = hist + w * nb;
    const int seg = TILE_EDGES / BWAVES;  // 512 edges per wave
    int wbeg = w * seg;
    int wend = min(wbeg + seg, cnt);
    for (int i = wbeg + lane; i < wend; i += 64) {
        int d = load_idx(raw, f, (long long)e + base + i);
        atomicAdd(&hw[d >> BIN_SHIFT], 1);
    }
    __syncthreads();
    for (int b = t; b < nb; b += 1024) {
        int s = 0;
#pragma unroll
        for (int w2 = 0; w2 < BWAVES; ++w2) s += hist[w2 * nb + b];
        mat[blockIdx.x * nb + b] = s;
        if (s) atomicAdd(&bin_tot[b], s);
    }
}

// Single-block exclusive scan over the 782 bin totals -> bin_base[0..nb],
// and initializes the global per-bin reservation cursors.
__global__ __launch_bounds__(1024)
void scanb_kernel(const int* __restrict__ bin_tot, int* __restrict__ bin_base,
                  int* __restrict__ cursor, int nb, int e) {
    __shared__ int sd[1024];
    int t = threadIdx.x;
    int v = (t < nb) ? bin_tot[t] : 0;
    sd[t] = v;
    __syncthreads();
    for (int off = 1; off < 1024; off <<= 1) {
        int add = (t >= off) ? sd[t - off] : 0;
        __syncthreads();
        sd[t] += add;
        __syncthreads();
    }
    if (t < nb) {
        int ex = sd[t] - v;
        bin_base[t] = ex;
        cursor[t] = ex;
    }
    if (t == nb) bin_base[nb] = e;
}

// Phase C: each block reserves a range per bin via one global atomicAdd of
// its tile count (order within bin nondeterministic - harmless), then
// scatters packed records through LDS cursors. rec = src | dst_local<<20.
__global__ __launch_bounds__(1024)
void binC_kernel(const void* __restrict__ raw, const int* __restrict__ mat,
                 int* __restrict__ cursor, int* __restrict__ packed,
                 int e, int nb) {
    extern __shared__ int cur[];  // nb + 1
    int t = threadIdx.x;
    int f = block_detect_int64((const int*)raw, &cur[nb]);
    for (int i = t; i < nb; i += 1024) {
        int c = mat[blockIdx.x * nb + i];
        cur[i] = c ? atomicAdd(&cursor[i], c) : 0;
    }
    __syncthreads();
    long long base = (long long)blockIdx.x * TILE_EDGES;
    int cnt = (int)min((long long)TILE_EDGES, (long long)e - base);
    for (int i = t; i < cnt; i += 1024) {
        long long ei = base + i;
        int s = load_idx(raw, f, ei);
        int d = load_idx(raw, f, (long long)e + ei);
        int b = d >> BIN_SHIFT;
        int pos = atomicAdd(&cur[b], 1);
        packed[pos] = s | ((d & (BIN_NODES - 1)) << SRC_BITS);
    }
}

// Per-bin: 16 wave-private LDS histograms -> scan -> dis/row_start + per-wave
// base cursors, then contention-free counting-sort (recs = src, 4B).
// FUSED layer-1 transform: h1[node] = fp16(dis*(x@W1)) with W1 in LDS.
__global__ __launch_bounds__(1024)
void degsort_kernel(const int* __restrict__ packed, const int* __restrict__ bin_base,
                    float* __restrict__ dis, int* __restrict__ row_start,
                    int* __restrict__ recs, const float* __restrict__ x,
                    const float* __restrict__ W1, __half* __restrict__ h1,
                    int e, int n, int nb) {
    __shared__ int cnt[BWAVES][BIN_NODES];   // 8 KB
    __shared__ int wcur[BWAVES][BIN_NODES];  // 8 KB
    __shared__ int exc[BIN_NODES];
    __shared__ float sdis[BIN_NODES];
    __shared__ float W1l[FEAT * FEAT];       // 4 KB
    __shared__ int stage[STAGE_CAP];         // 24 KB
    int b = blockIdx.x, t = threadIdx.x;
    int w = t >> 6;
    for (int i = t; i < BWAVES * BIN_NODES; i += 1024) ((int*)cnt)[i] = 0;
    if (t < FEAT * FEAT) W1l[t] = W1[t];   // 1024 threads, 1024 elems
    __syncthreads();
    int start = bin_base[b];
    int end = bin_base[b + 1];
    int m = end - start;
    if (m <= STAGE_CAP) {
        for (int i = t; i < m; i += 1024) {
            int rec = packed[start + i];
            stage[i] = rec;
            atomicAdd(&cnt[w][rec >> SRC_BITS], 1);
        }
    } else {
        for (int i = start + t; i < end; i += 1024)
            atomicAdd(&cnt[w][packed[i] >> SRC_BITS], 1);
    }
    __syncthreads();
    if (t < BIN_NODES) {
        int s = 0;
#pragma unroll
        for (int w2 = 0; w2 < BWAVES; ++w2) s += cnt[w2][t];
        exc[t] = s;
    }
    __syncthreads();
    for (int off = 1; off < BIN_NODES; off <<= 1) {
        int v = 0;
        if (t < BIN_NODES && t >= off) v = exc[t - off];
        __syncthreads();
        if (t < BIN_NODES) exc[t] += v;
        __syncthreads();
    }
    if (t < BIN_NODES) {
        int tot = 0;
#pragma unroll
        for (int w2 = 0; w2 < BWAVES; ++w2) tot += cnt[w2][t];
        int rs = start + exc[t] - tot;   // inclusive -> exclusive
        int run = rs;
#pragma unroll
        for (int w2 = 0; w2 < BWAVES; ++w2) { wcur[w2][t] = run; run += cnt[w2][t]; }
        float dv = rsqrtf((float)tot + 1.0f);
        sdis[t] = dv;
        int node = b * BIN_NODES + t;
        if (node < n) {
            dis[node] = dv;
            row_start[node] = rs;
        }
    }
    if (b == 0 && t == 128) row_start[n] = e;  // sentinel
    __syncthreads();
    if (m <= STAGE_CAP) {
        for (int i = t; i < m; i += 1024) {
            int rec = stage[i];
            int pos = atomicAdd(&wcur[w][rec >> SRC_BITS], 1);
            recs[pos] = rec & SRC_MASK;
        }
    } else {
        for (int i = start + t; i < end; i += 1024) {
            int rec = packed[i];
            int pos = atomicAdd(&wcur[w][rec >> SRC_BITS], 1);
            recs[pos] = rec & SRC_MASK;
        }
    }
    // fused mm1: 8 threads/node, each thread holds one float4 of the x-row and
    // produces 4 output features; 8-wide shfl broadcasts the x values.
    {
        int ln = b * BIN_NODES + (t >> 3);
        if (ln < n) {
            int q = t & 7;
            float4 xv = ((const float4*)x)[(size_t)ln * 8 + q];
            float xr[4] = {xv.x, xv.y, xv.z, xv.w};
            float o[4] = {0.f, 0.f, 0.f, 0.f};
#pragma unroll
            for (int k = 0; k < FEAT; ++k) {
                float xk = __shfl(xr[k & 3], k >> 2, 8);
#pragma unroll
                for (int c = 0; c < 4; ++c)
                    o[c] = fmaf(xk, W1l[k * FEAT + q * 4 + c], o[c]);
            }
            float dn = sdis[t >> 3];
            __half2* hp = (__half2*)&h1[(size_t)ln * FEAT + q * 4];
            hp[0] = __halves2half2(__float2half(dn * o[0]), __float2half(dn * o[1]));
            hp[1] = __halves2half2(__float2half(dn * o[2]), __float2half(dn * o[3]));
        }
    }
}

// Layer-1 pull FUSED with layer-2 transform, 16 lanes/node (4 slots x 4
// feature-quads): 4 gathers in flight per lane, 2-level slot butterfly, then
// mm2 as distributed 8x8 register blocks + 2-level fb butterfly (no serial
// shfl-fma chain). W2 staged in LDS with per-k-block column rotation so the
// 16-lane read pattern is bank-conflict-free.
__global__ __launch_bounds__(256, 8)
void pull_mm_kernel(const int* __restrict__ recs, const int* __restrict__ row_start,
                    const __half* __restrict__ h, const float* __restrict__ dis,
                    const float* __restrict__ bias, const float* __restrict__ W2,
                    __half* __restrict__ h2, int n) {
    __shared__ float Wl[FEAT * FEAT];
    int t = threadIdx.x;
    for (int i = t; i < FEAT * FEAT; i += 256) {
        int k = i >> 5, j = i & 31;
        int col = (j & 24) | ((j + 2 * (k >> 3)) & 7);   // rotate within 8-block
        Wl[k * FEAT + col] = W2[i];
    }
    __syncthreads();
    int node = blockIdx.x * 16 + (t >> 4);
    if (node >= n) return;
    int g = t & 15;
    int sub = g >> 2;   // record slot 0..3
    int fb = g & 3;     // float4 feature block (8 halves)
    int start = row_start[node];
    int deg = row_start[node + 1] - start;
    const float4* h4 = (const float4*)h;  // 8 halves per float4, 4 per row
    float s0 = 0, s1 = 0, s2 = 0, s3 = 0, s4 = 0, s5 = 0, s6 = 0, s7 = 0;
    for (int r0 = 0; r0 < deg; r0 += 32) {
#pragma unroll
        for (int w = 0; w < 8; ++w) {
            int r = r0 + w * 4 + sub;
            if (r < deg) {
                int s = recs[start + r];
                float4 v = h4[(size_t)s * 4 + fb];
                const __half2* hp = (const __half2*)&v;
                float2 a = __half22float2(hp[0]);
                float2 b = __half22float2(hp[1]);
                float2 c = __half22float2(hp[2]);
                float2 d = __half22float2(hp[3]);
                s0 += a.x; s1 += a.y; s2 += b.x; s3 += b.y;
                s4 += c.x; s5 += c.y; s6 += d.x; s7 += d.y;
            }
        }
    }
    // 2-level butterfly over slots (xor 4, 8) -> all 16 lanes hold fb totals
#pragma unroll
    for (int m = 4; m <= 8; m <<= 1) {
        s0 += __shfl_xor(s0, m, 64); s1 += __shfl_xor(s1, m, 64);
        s2 += __shfl_xor(s2, m, 64); s3 += __shfl_xor(s3, m, 64);
        s4 += __shfl_xor(s4, m, 64); s5 += __shfl_xor(s5, m, 64);
        s6 += __shfl_xor(s6, m, 64); s7 += __shfl_xor(s7, m, 64);
    }
    float dn = dis[node];
    float4 hv = h4[(size_t)node * 4 + fb];   // self-loop: + h~[node]
    const __half2* hp = (const __half2*)&hv;
    float2 a = __half22float2(hp[0]);
    float2 b = __half22float2(hp[1]);
    float2 c = __half22float2(hp[2]);
    float2 d = __half22float2(hp[3]);
    const float4* bv4 = (const float4*)bias;
    float4 b0 = bv4[fb * 2], b1 = bv4[fb * 2 + 1];
    float o[8];
    o[0] = fmaxf(fmaf(dn, s0 + a.x, b0.x), 0.0f);
    o[1] = fmaxf(fmaf(dn, s1 + a.y, b0.y), 0.0f);
    o[2] = fmaxf(fmaf(dn, s2 + b.x, b0.z), 0.0f);
    o[3] = fmaxf(fmaf(dn, s3 + b.y, b0.w), 0.0f);
    o[4] = fmaxf(fmaf(dn, s4 + c.x, b1.x), 0.0f);
    o[5] = fmaxf(fmaf(dn, s5 + c.y, b1.y), 0.0f);
    o[6] = fmaxf(fmaf(dn, s6 + d.x, b1.z), 0.0f);
    o[7] = fmaxf(fmaf(dn, s7 + d.y, b1.w), 0.0f);
    // mm2: lane (sub,fb) computes the 8x8 block k in [8fb,8fb+8) x j in
    // [8sub,8sub+8) of relu(out1) @ W2, entirely from registers + LDS.
    float part[8] = {0.f, 0.f, 0.f, 0.f, 0.f, 0.f, 0.f, 0.f};
    const float* wrow = &Wl[(fb * 8) * FEAT + sub * 8];
#pragma unroll
    for (int cc = 0; cc < 8; ++cc) {
#pragma unroll
        for (int c2 = 0; c2 < 8; ++c2)
            part[c2] = fmaf(o[cc], wrow[cc * FEAT + ((c2 + 2 * fb) & 7)], part[c2]);
    }
    // 2-level butterfly over fb (xor 1, 2) -> full k-sum for features 8sub+c2
#pragma unroll
    for (int m = 1; m <= 2; m <<= 1) {
        part[0] += __shfl_xor(part[0], m, 64); part[1] += __shfl_xor(part[1], m, 64);
        part[2] += __shfl_xor(part[2], m, 64); part[3] += __shfl_xor(part[3], m, 64);
        part[4] += __shfl_xor(part[4], m, 64); part[5] += __shfl_xor(part[5], m, 64);
        part[6] += __shfl_xor(part[6], m, 64); part[7] += __shfl_xor(part[7], m, 64);
    }
    if (fb == 0) {
        __half2 p0 = __halves2half2(__float2half(dn * part[0]), __float2half(dn * part[1]));
        __half2 p1 = __halves2half2(__float2half(dn * part[2]), __float2half(dn * part[3]));
        __half2 p2 = __halves2half2(__float2half(dn * part[4]), __float2half(dn * part[5]));
        __half2 p3 = __halves2half2(__float2half(dn * part[6]), __float2half(dn * part[7]));
        float4 pk;
        ((__half2*)&pk)[0] = p0; ((__half2*)&pk)[1] = p1;
        ((__half2*)&pk)[2] = p2; ((__half2*)&pk)[3] = p3;
        ((float4*)h2)[(size_t)node * 4 + sub] = pk;  // features 8sub..8sub+7
    }
}

// Final pull, 16 lanes/node: out[d] = relu( dis[d]*(sum h~[s] + h~[d]) + b ).
__global__ __launch_bounds__(256, 8)
void pull_kernel(const int* __restrict__ recs, const int* __restrict__ row_start,
                 const __half* __restrict__ h, const float* __restrict__ dis,
                 const float* __restrict__ bias, float* __restrict__ out, int n) {
    int t = threadIdx.x;
    int node = blockIdx.x * 16 + (t >> 4);
    if (node >= n) return;
    int g = t & 15;
    int sub = g >> 2;   // record slot 0..3
    int fb = g & 3;     // float4 feature block (8 halves)
    int start = row_start[node];
    int deg = row_start[node + 1] - start;
    const float4* h4 = (const float4*)h;  // 8 halves per float4, 4 per row
    float s0 = 0, s1 = 0, s2 = 0, s3 = 0, s4 = 0, s5 = 0, s6 = 0, s7 = 0;
    for (int r0 = 0; r0 < deg; r0 += 32) {
#pragma unroll
        for (int w = 0; w < 8; ++w) {
            int r = r0 + w * 4 + sub;
            if (r < deg) {
                int s = recs[start + r];
                float4 v = h4[(size_t)s * 4 + fb];
                const __half2* hp = (const __half2*)&v;
                float2 a = __half22float2(hp[0]);
                float2 b = __half22float2(hp[1]);
                float2 c = __half22float2(hp[2]);
                float2 d = __half22float2(hp[3]);
                s0 += a.x; s1 += a.y; s2 += b.x; s3 += b.y;
                s4 += c.x; s5 += c.y; s6 += d.x; s7 += d.y;
            }
        }
    }
#pragma unroll
    for (int m = 4; m <= 8; m <<= 1) {
        s0 += __shfl_xor(s0, m, 64); s1 += __shfl_xor(s1, m, 64);
        s2 += __shfl_xor(s2, m, 64); s3 += __shfl_xor(s3, m, 64);
        s4 += __shfl_xor(s4, m, 64); s5 += __shfl_xor(s5, m, 64);
        s6 += __shfl_xor(s6, m, 64); s7 += __shfl_xor(s7, m, 64);
    }
    if (sub == 0) {
        float dn = dis[node];
        float4 hv = h4[(size_t)node * 4 + fb];   // self-loop: + h~[node]
        const __half2* hp = (const __half2*)&hv;
        float2 a = __half22float2(hp[0]);
        float2 b = __half22float2(hp[1]);
        float2 c = __half22float2(hp[2]);
        float2 d = __half22float2(hp[3]);
        const float4* bv4 = (const float4*)bias;
        float4 b0 = bv4[fb * 2], b1 = bv4[fb * 2 + 1];
        float4 o0, o1;
        o0.x = fmaxf(fmaf(dn, s0 + a.x, b0.x), 0.0f);
        o0.y = fmaxf(fmaf(dn, s1 + a.y, b0.y), 0.0f);
        o0.z = fmaxf(fmaf(dn, s2 + b.x, b0.z), 0.0f);
        o0.w = fmaxf(fmaf(dn, s3 + b.y, b0.w), 0.0f);
        o1.x = fmaxf(fmaf(dn, s4 + c.x, b1.x), 0.0f);
        o1.y = fmaxf(fmaf(dn, s5 + c.y, b1.y), 0.0f);
        o1.z = fmaxf(fmaf(dn, s6 + d.x, b1.z), 0.0f);
        o1.w = fmaxf(fmaf(dn, s7 + d.y, b1.w), 0.0f);
        ((float4*)out)[(size_t)node * 8 + fb * 2] = o0;
        ((float4*)out)[(size_t)node * 8 + fb * 2 + 1] = o1;
    }
}

extern "C" void kernel_launch(void* const* d_in, const int* in_sizes, int n_in,
                              void* d_out, int out_size, void* d_ws, size_t ws_size,
                              hipStream_t stream) {
    const float* x = (const float*)d_in[0];
    const void* eidx_raw = d_in[1];
    const float* W1 = (const float*)d_in[2];
    const float* b1 = (const float*)d_in[3];
    const float* W2 = (const float*)d_in[4];
    const float* b2 = (const float*)d_in[5];
    float* out = (float*)d_out;

    const int n = in_sizes[0] / FEAT;                    // 100000
    const int e = in_sizes[1] / 2;                       // 1600000
    const int nb = (n + BIN_NODES - 1) / BIN_NODES;      // 782
    const int nblk = (e + TILE_EDGES - 1) / TILE_EDGES;  // 196
    const int M = nb * nblk;                             // 153k

    // Workspace (256B-aligned). `packed` aliases `h2` (packed dead after
    // degsort; h2 first written by pull_mm; both exactly e*4 == n*64 bytes).
    char* ws = (char*)d_ws;
    size_t off = 0;
    auto alloc = [&](size_t bytes) { char* p = ws + off; off = (off + bytes + 255) & ~(size_t)255; return p; };
    int*    mat       = (int*)   alloc((size_t)M * 4);
    int*    bin_tot   = (int*)   alloc((size_t)nb * 4);
    int*    bin_base  = (int*)   alloc((size_t)(nb + 1) * 4);
    int*    cursor    = (int*)   alloc((size_t)nb * 4);
    float*  dis       = (float*) alloc((size_t)n * 4);
    int*    row_start = (int*)   alloc((size_t)(n + 1) * 4);
    int*    recs      = (int*)   alloc((size_t)e * 4);
    __half* h1        = (__half*)alloc((size_t)n * FEAT * 2);
    __half* h2        = (__half*)alloc((size_t)(n * FEAT * 2 > e * 4 ? (size_t)n * FEAT * 2 : (size_t)e * 4));
    int*    packed    = (int*)h2;

    const size_t ldsA = (size_t)(BWAVES * nb + 1) * 4;   // ~50 KB
    const size_t ldsC = (size_t)(nb + 1) * 4;            // ~3.1 KB
    const int gNode = (n + 15) / 16;

    // CSR build (reservation-based: no 153K scan)
    hipMemsetAsync(bin_tot, 0, (size_t)nb * 4, stream);
    binA_kernel<<<nblk, 1024, ldsA, stream>>>(eidx_raw, mat, bin_tot, e, nb);
    scanb_kernel<<<1, 1024, 0, stream>>>(bin_tot, bin_base, cursor, nb, e);
    binC_kernel<<<nblk, 1024, ldsC, stream>>>(eidx_raw, mat, cursor, packed, e, nb);
    // degsort (LDS-staged) + fused layer-1 transform (x@W1 -> h1)
    degsort_kernel<<<nb, 1024, 0, stream>>>(packed, bin_base, dis, row_start,
                                            recs, x, W1, h1, e, n, nb);

    // Layer-1 aggregate + fused layer-2 transform (-> h2)
    pull_mm_kernel<<<gNode, 256, 0, stream>>>(recs, row_start, h1, dis, b1, W2, h2, n);
    // Layer-2 aggregate + bias + final relu
    pull_kernel<<<gNode, 256, 0, stream>>>(recs, row_start, h2, dis, b2, out, n);
}

// Round 7
// 177.396 us; speedup vs baseline: 3.2544x; 1.0564x over previous
//
#include <hip/hip_runtime.h>
#include <hip/hip_fp16.h>

#define FEAT 32
#define BIN_NODES 128
#define BIN_SHIFT 7
#define TILE_EDGES 8192   // edges per build block
#define BWAVES 16         // waves in a 1024-thread block
#define NC 8              // histogram copies in binAC
#define SRC_BITS 20
#define SRC_MASK 0xFFFFF
#define STAGE_CAP 6144    // LDS staging cap for a bin's packed edges (24 KB)

__device__ __forceinline__ int load_idx(const void* raw, int f, long long i) {
    return f ? (int)((const long long*)raw)[i] : ((const int*)raw)[i];
}

// cursor[b] = b*cap  (slot base for bin b in the slotted packed buffer)
__global__ __launch_bounds__(1024)
void initc_kernel(int* __restrict__ cursor, int nb, int cap) {
    int t = threadIdx.x;
    if (t < nb) cursor[t] = t * cap;
}

// Fused binA+binC: ONE pass over the edge list. Tile -> registers (8/thread),
// 8-copy LDS histogram of this tile, per-bin range reservation via one global
// atomicAdd per non-empty bin (order within bin nondeterministic - harmless,
// degsort re-sorts by node), scatter packed recs from registers into the
// bin's slot. rec = src | dst_local<<20.
__global__ __launch_bounds__(1024)
void binAC_kernel(const void* __restrict__ raw, int* __restrict__ cursor,
                  int* __restrict__ packed, int e, int nb) {
    extern __shared__ int lds[];   // NC*nb (hist) + nb (cur) + 1 (nz)
    int t = threadIdx.x;
    int* hist = lds;
    int* cur  = lds + NC * nb;
    int* nz   = lds + NC * nb + nb;
    for (int i = t; i < NC * nb; i += 1024) hist[i] = 0;
    if (t == 0) *nz = 0;
    __syncthreads();
    if (((const int*)raw)[2 * t + 1] != 0) *nz = 1;   // int64 detect (benign race)
    __syncthreads();
    const int f = (*nz == 0) ? 1 : 0;

    long long base = (long long)blockIdx.x * TILE_EDGES;
    int cnt = (int)min((long long)TILE_EDGES, (long long)e - base);
    int sreg[8], dreg[8];
    int* hw = hist + ((t >> 6) & (NC - 1)) * nb;   // 2 waves per copy
#pragma unroll
    for (int k = 0; k < 8; ++k) {
        int i = t + k * 1024;
        if (i < cnt) {
            sreg[k] = load_idx(raw, f, base + i);
            dreg[k] = load_idx(raw, f, (long long)e + base + i);
            atomicAdd(&hw[dreg[k] >> BIN_SHIFT], 1);
        } else {
            dreg[k] = -1;
        }
    }
    __syncthreads();
    for (int b = t; b < nb; b += 1024) {
        int s = 0;
#pragma unroll
        for (int c = 0; c < NC; ++c) s += hist[c * nb + b];
        cur[b] = s ? atomicAdd(&cursor[b], s) : 0;
    }
    __syncthreads();
#pragma unroll
    for (int k = 0; k < 8; ++k) {
        int d = dreg[k];
        if (d >= 0) {
            int pos = atomicAdd(&cur[d >> BIN_SHIFT], 1);
            packed[pos] = sreg[k] | ((d & (BIN_NODES - 1)) << SRC_BITS);
        }
    }
}

// Single-block scan: cnt_b = cursor[b] - b*cap -> exclusive scan -> bin_base.
__global__ __launch_bounds__(1024)
void scanb_kernel(const int* __restrict__ cursor, int* __restrict__ bin_base,
                  int nb, int cap, int e) {
    __shared__ int sd[1024];
    int t = threadIdx.x;
    int v = (t < nb) ? (cursor[t] - t * cap) : 0;
    sd[t] = v;
    __syncthreads();
    for (int off = 1; off < 1024; off <<= 1) {
        int add = (t >= off) ? sd[t - off] : 0;
        __syncthreads();
        sd[t] += add;
        __syncthreads();
    }
    if (t < nb) bin_base[t] = sd[t] - v;
    if (t == nb) bin_base[nb] = e;
}

// Per-bin: 16 wave-private LDS histograms -> scan -> dis/row_start + per-wave
// base cursors, then contention-free counting-sort (recs = src, 4B).
// Reads the bin's slot [b*cap, b*cap+m) of packed; writes recs densely at
// bin_base[b]. FUSED layer-1 transform: h1 = fp16(dis*(x@W1)), W1 in LDS.
__global__ __launch_bounds__(1024)
void degsort_kernel(const int* __restrict__ packed, const int* __restrict__ bin_base,
                    float* __restrict__ dis, int* __restrict__ row_start,
                    int* __restrict__ recs, const float* __restrict__ x,
                    const float* __restrict__ W1, __half* __restrict__ h1,
                    int e, int n, int nb, int cap) {
    __shared__ int cnt[BWAVES][BIN_NODES];   // 8 KB
    __shared__ int wcur[BWAVES][BIN_NODES];  // 8 KB
    __shared__ int exc[BIN_NODES];
    __shared__ float sdis[BIN_NODES];
    __shared__ float W1l[FEAT * FEAT];       // 4 KB
    __shared__ int stage[STAGE_CAP];         // 24 KB
    int b = blockIdx.x, t = threadIdx.x;
    int w = t >> 6;
    for (int i = t; i < BWAVES * BIN_NODES; i += 1024) ((int*)cnt)[i] = 0;
    if (t < FEAT * FEAT) W1l[t] = W1[t];   // 1024 threads, 1024 elems
    __syncthreads();
    int start = bin_base[b];
    int m = bin_base[b + 1] - start;
    long long pbase = (long long)b * cap;
    if (m <= STAGE_CAP) {
        for (int i = t; i < m; i += 1024) {
            int rec = packed[pbase + i];
            stage[i] = rec;
            atomicAdd(&cnt[w][rec >> SRC_BITS], 1);
        }
    } else {
        for (int i = t; i < m; i += 1024)
            atomicAdd(&cnt[w][packed[pbase + i] >> SRC_BITS], 1);
    }
    __syncthreads();
    if (t < BIN_NODES) {
        int s = 0;
#pragma unroll
        for (int w2 = 0; w2 < BWAVES; ++w2) s += cnt[w2][t];
        exc[t] = s;
    }
    __syncthreads();
    for (int off = 1; off < BIN_NODES; off <<= 1) {
        int v = 0;
        if (t < BIN_NODES && t >= off) v = exc[t - off];
        __syncthreads();
        if (t < BIN_NODES) exc[t] += v;
        __syncthreads();
    }
    if (t < BIN_NODES) {
        int tot = 0;
#pragma unroll
        for (int w2 = 0; w2 < BWAVES; ++w2) tot += cnt[w2][t];
        int rs = start + exc[t] - tot;   // inclusive -> exclusive
        int run = rs;
#pragma unroll
        for (int w2 = 0; w2 < BWAVES; ++w2) { wcur[w2][t] = run; run += cnt[w2][t]; }
        float dv = rsqrtf((float)tot + 1.0f);
        sdis[t] = dv;
        int node = b * BIN_NODES + t;
        if (node < n) {
            dis[node] = dv;
            row_start[node] = rs;
        }
    }
    if (b == 0 && t == 128) row_start[n] = e;  // sentinel
    __syncthreads();
    if (m <= STAGE_CAP) {
        for (int i = t; i < m; i += 1024) {
            int rec = stage[i];
            int pos = atomicAdd(&wcur[w][rec >> SRC_BITS], 1);
            recs[pos] = rec & SRC_MASK;
        }
    } else {
        for (int i = t; i < m; i += 1024) {
            int rec = packed[pbase + i];
            int pos = atomicAdd(&wcur[w][rec >> SRC_BITS], 1);
            recs[pos] = rec & SRC_MASK;
        }
    }
    // fused mm1: 8 threads/node, each thread holds one float4 of the x-row and
    // produces 4 output features; 8-wide shfl broadcasts the x values.
    {
        int ln = b * BIN_NODES + (t >> 3);
        if (ln < n) {
            int q = t & 7;
            float4 xv = ((const float4*)x)[(size_t)ln * 8 + q];
            float xr[4] = {xv.x, xv.y, xv.z, xv.w};
            float o[4] = {0.f, 0.f, 0.f, 0.f};
#pragma unroll
            for (int k = 0; k < FEAT; ++k) {
                float xk = __shfl(xr[k & 3], k >> 2, 8);
#pragma unroll
                for (int c = 0; c < 4; ++c)
                    o[c] = fmaf(xk, W1l[k * FEAT + q * 4 + c], o[c]);
            }
            float dn = sdis[t >> 3];
            __half2* hp = (__half2*)&h1[(size_t)ln * FEAT + q * 4];
            hp[0] = __halves2half2(__float2half(dn * o[0]), __float2half(dn * o[1]));
            hp[1] = __halves2half2(__float2half(dn * o[2]), __float2half(dn * o[3]));
        }
    }
}

// Layer-1 pull FUSED with layer-2 transform, 16 lanes/node (4 slots x 4
// feature-quads): 4 gathers in flight per lane, 2-level slot butterfly, then
// mm2 as distributed 8x8 register blocks + 2-level fb butterfly (no serial
// shfl-fma chain). W2 staged in LDS with per-k-block column rotation so the
// 16-lane read pattern is bank-conflict-free.
__global__ __launch_bounds__(256, 8)
void pull_mm_kernel(const int* __restrict__ recs, const int* __restrict__ row_start,
                    const __half* __restrict__ h, const float* __restrict__ dis,
                    const float* __restrict__ bias, const float* __restrict__ W2,
                    __half* __restrict__ h2, int n) {
    __shared__ float Wl[FEAT * FEAT];
    int t = threadIdx.x;
    for (int i = t; i < FEAT * FEAT; i += 256) {
        int k = i >> 5, j = i & 31;
        int col = (j & 24) | ((j + 2 * (k >> 3)) & 7);   // rotate within 8-block
        Wl[k * FEAT + col] = W2[i];
    }
    __syncthreads();
    int node = blockIdx.x * 16 + (t >> 4);
    if (node >= n) return;
    int g = t & 15;
    int sub = g >> 2;   // record slot 0..3
    int fb = g & 3;     // float4 feature block (8 halves)
    int start = row_start[node];
    int deg = row_start[node + 1] - start;
    const float4* h4 = (const float4*)h;  // 8 halves per float4, 4 per row
    float s0 = 0, s1 = 0, s2 = 0, s3 = 0, s4 = 0, s5 = 0, s6 = 0, s7 = 0;
    for (int r0 = 0; r0 < deg; r0 += 32) {
#pragma unroll
        for (int w = 0; w < 8; ++w) {
            int r = r0 + w * 4 + sub;
            if (r < deg) {
                int s = recs[start + r];
                float4 v = h4[(size_t)s * 4 + fb];
                const __half2* hp = (const __half2*)&v;
                float2 a = __half22float2(hp[0]);
                float2 b = __half22float2(hp[1]);
                float2 c = __half22float2(hp[2]);
                float2 d = __half22float2(hp[3]);
                s0 += a.x; s1 += a.y; s2 += b.x; s3 += b.y;
                s4 += c.x; s5 += c.y; s6 += d.x; s7 += d.y;
            }
        }
    }
    // 2-level butterfly over slots (xor 4, 8) -> all 16 lanes hold fb totals
#pragma unroll
    for (int m = 4; m <= 8; m <<= 1) {
        s0 += __shfl_xor(s0, m, 64); s1 += __shfl_xor(s1, m, 64);
        s2 += __shfl_xor(s2, m, 64); s3 += __shfl_xor(s3, m, 64);
        s4 += __shfl_xor(s4, m, 64); s5 += __shfl_xor(s5, m, 64);
        s6 += __shfl_xor(s6, m, 64); s7 += __shfl_xor(s7, m, 64);
    }
    float dn = dis[node];
    float4 hv = h4[(size_t)node * 4 + fb];   // self-loop: + h~[node]
    const __half2* hp = (const __half2*)&hv;
    float2 a = __half22float2(hp[0]);
    float2 b = __half22float2(hp[1]);
    float2 c = __half22float2(hp[2]);
    float2 d = __half22float2(hp[3]);
    const float4* bv4 = (const float4*)bias;
    float4 b0 = bv4[fb * 2], b1 = bv4[fb * 2 + 1];
    float o[8];
    o[0] = fmaxf(fmaf(dn, s0 + a.x, b0.x), 0.0f);
    o[1] = fmaxf(fmaf(dn, s1 + a.y, b0.y), 0.0f);
    o[2] = fmaxf(fmaf(dn, s2 + b.x, b0.z), 0.0f);
    o[3] = fmaxf(fmaf(dn, s3 + b.y, b0.w), 0.0f);
    o[4] = fmaxf(fmaf(dn, s4 + c.x, b1.x), 0.0f);
    o[5] = fmaxf(fmaf(dn, s5 + c.y, b1.y), 0.0f);
    o[6] = fmaxf(fmaf(dn, s6 + d.x, b1.z), 0.0f);
    o[7] = fmaxf(fmaf(dn, s7 + d.y, b1.w), 0.0f);
    // mm2: lane (sub,fb) computes the 8x8 block k in [8fb,8fb+8) x j in
    // [8sub,8sub+8) of relu(out1) @ W2, entirely from registers + LDS.
    float part[8] = {0.f, 0.f, 0.f, 0.f, 0.f, 0.f, 0.f, 0.f};
    const float* wrow = &Wl[(fb * 8) * FEAT + sub * 8];
#pragma unroll
    for (int cc = 0; cc < 8; ++cc) {
#pragma unroll
        for (int c2 = 0; c2 < 8; ++c2)
            part[c2] = fmaf(o[cc], wrow[cc * FEAT + ((c2 + 2 * fb) & 7)], part[c2]);
    }
    // 2-level butterfly over fb (xor 1, 2) -> full k-sum for features 8sub+c2
#pragma unroll
    for (int m = 1; m <= 2; m <<= 1) {
        part[0] += __shfl_xor(part[0], m, 64); part[1] += __shfl_xor(part[1], m, 64);
        part[2] += __shfl_xor(part[2], m, 64); part[3] += __shfl_xor(part[3], m, 64);
        part[4] += __shfl_xor(part[4], m, 64); part[5] += __shfl_xor(part[5], m, 64);
        part[6] += __shfl_xor(part[6], m, 64); part[7] += __shfl_xor(part[7], m, 64);
    }
    if (fb == 0) {
        __half2 p0 = __halves2half2(__float2half(dn * part[0]), __float2half(dn * part[1]));
        __half2 p1 = __halves2half2(__float2half(dn * part[2]), __float2half(dn * part[3]));
        __half2 p2 = __halves2half2(__float2half(dn * part[4]), __float2half(dn * part[5]));
        __half2 p3 = __halves2half2(__float2half(dn * part[6]), __float2half(dn * part[7]));
        float4 pk;
        ((__half2*)&pk)[0] = p0; ((__half2*)&pk)[1] = p1;
        ((__half2*)&pk)[2] = p2; ((__half2*)&pk)[3] = p3;
        ((float4*)h2)[(size_t)node * 4 + sub] = pk;  // features 8sub..8sub+7
    }
}

// Final pull, 16 lanes/node: out[d] = relu( dis[d]*(sum h~[s] + h~[d]) + b ).
__global__ __launch_bounds__(256, 8)
void pull_kernel(const int* __restrict__ recs, const int* __restrict__ row_start,
                 const __half* __restrict__ h, const float* __restrict__ dis,
                 const float* __restrict__ bias, float* __restrict__ out, int n) {
    int t = threadIdx.x;
    int node = blockIdx.x * 16 + (t >> 4);
    if (node >= n) return;
    int g = t & 15;
    int sub = g >> 2;   // record slot 0..3
    int fb = g & 3;     // float4 feature block (8 halves)
    int start = row_start[node];
    int deg = row_start[node + 1] - start;
    const float4* h4 = (const float4*)h;  // 8 halves per float4, 4 per row
    float s0 = 0, s1 = 0, s2 = 0, s3 = 0, s4 = 0, s5 = 0, s6 = 0, s7 = 0;
    for (int r0 = 0; r0 < deg; r0 += 32) {
#pragma unroll
        for (int w = 0; w < 8; ++w) {
            int r = r0 + w * 4 + sub;
            if (r < deg) {
                int s = recs[start + r];
                float4 v = h4[(size_t)s * 4 + fb];
                const __half2* hp = (const __half2*)&v;
                float2 a = __half22float2(hp[0]);
                float2 b = __half22float2(hp[1]);
                float2 c = __half22float2(hp[2]);
                float2 d = __half22float2(hp[3]);
                s0 += a.x; s1 += a.y; s2 += b.x; s3 += b.y;
                s4 += c.x; s5 += c.y; s6 += d.x; s7 += d.y;
            }
        }
    }
#pragma unroll
    for (int m = 4; m <= 8; m <<= 1) {
        s0 += __shfl_xor(s0, m, 64); s1 += __shfl_xor(s1, m, 64);
        s2 += __shfl_xor(s2, m, 64); s3 += __shfl_xor(s3, m, 64);
        s4 += __shfl_xor(s4, m, 64); s5 += __shfl_xor(s5, m, 64);
        s6 += __shfl_xor(s6, m, 64); s7 += __shfl_xor(s7, m, 64);
    }
    if (sub == 0) {
        float dn = dis[node];
        float4 hv = h4[(size_t)node * 4 + fb];   // self-loop: + h~[node]
        const __half2* hp = (const __half2*)&hv;
        float2 a = __half22float2(hp[0]);
        float2 b = __half22float2(hp[1]);
        float2 c = __half22float2(hp[2]);
        float2 d = __half22float2(hp[3]);
        const float4* bv4 = (const float4*)bias;
        float4 b0 = bv4[fb * 2], b1 = bv4[fb * 2 + 1];
        float4 o0, o1;
        o0.x = fmaxf(fmaf(dn, s0 + a.x, b0.x), 0.0f);
        o0.y = fmaxf(fmaf(dn, s1 + a.y, b0.y), 0.0f);
        o0.z = fmaxf(fmaf(dn, s2 + b.x, b0.z), 0.0f);
        o0.w = fmaxf(fmaf(dn, s3 + b.y, b0.w), 0.0f);
        o1.x = fmaxf(fmaf(dn, s4 + c.x, b1.x), 0.0f);
        o1.y = fmaxf(fmaf(dn, s5 + c.y, b1.y), 0.0f);
        o1.z = fmaxf(fmaf(dn, s6 + d.x, b1.z), 0.0f);
        o1.w = fmaxf(fmaf(dn, s7 + d.y, b1.w), 0.0f);
        ((float4*)out)[(size_t)node * 8 + fb * 2] = o0;
        ((float4*)out)[(size_t)node * 8 + fb * 2 + 1] = o1;
    }
}

extern "C" void kernel_launch(void* const* d_in, const int* in_sizes, int n_in,
                              void* d_out, int out_size, void* d_ws, size_t ws_size,
                              hipStream_t stream) {
    const float* x = (const float*)d_in[0];
    const void* eidx_raw = d_in[1];
    const float* W1 = (const float*)d_in[2];
    const float* b1 = (const float*)d_in[3];
    const float* W2 = (const float*)d_in[4];
    const float* b2 = (const float*)d_in[5];
    float* out = (float*)d_out;

    const int n = in_sizes[0] / FEAT;                    // 100000
    const int e = in_sizes[1] / 2;                       // 1600000
    const int nb = (n + BIN_NODES - 1) / BIN_NODES;      // 782
    const int nblk = (e + TILE_EDGES - 1) / TILE_EDGES;  // 196
    const int avg = (e + nb - 1) / nb;                   // ~2046
    const int cap = (avg + (avg >> 1) + 255) & ~255;     // 3072 (~22 sigma)

    // Workspace (256B-aligned). `packed` (slotted, nb*cap ints) aliases `h2`
    // (packed dead after degsort; h2 first written by pull_mm).
    char* ws = (char*)d_ws;
    size_t off = 0;
    auto alloc = [&](size_t bytes) { char* p = ws + off; off = (off + bytes + 255) & ~(size_t)255; return p; };
    int*    cursor    = (int*)   alloc((size_t)nb * 4);
    int*    bin_base  = (int*)   alloc((size_t)(nb + 1) * 4);
    float*  dis       = (float*) alloc((size_t)n * 4);
    int*    row_start = (int*)   alloc((size_t)(n + 1) * 4);
    int*    recs      = (int*)   alloc((size_t)e * 4);
    __half* h1        = (__half*)alloc((size_t)n * FEAT * 2);
    size_t  packed_bytes = (size_t)nb * cap * 4;
    size_t  h2_bytes     = (size_t)n * FEAT * 2;
    __half* h2        = (__half*)alloc(packed_bytes > h2_bytes ? packed_bytes : h2_bytes);
    int*    packed    = (int*)h2;

    const size_t ldsAC = (size_t)(NC * nb + nb + 1) * 4;   // ~27.5 KB
    const int gNode = (n + 15) / 16;

    // CSR build: edge list read exactly once (binAC), tiny scan, degsort.
    initc_kernel<<<1, 1024, 0, stream>>>(cursor, nb, cap);
    binAC_kernel<<<nblk, 1024, ldsAC, stream>>>(eidx_raw, cursor, packed, e, nb);
    scanb_kernel<<<1, 1024, 0, stream>>>(cursor, bin_base, nb, cap, e);
    degsort_kernel<<<nb, 1024, 0, stream>>>(packed, bin_base, dis, row_start,
                                            recs, x, W1, h1, e, n, nb, cap);

    // Layer-1 aggregate + fused layer-2 transform (-> h2)
    pull_mm_kernel<<<gNode, 256, 0, stream>>>(recs, row_start, h1, dis, b1, W2, h2, n);
    // Layer-2 aggregate + bias + final relu
    pull_kernel<<<gNode, 256, 0, stream>>>(recs, row_start, h2, dis, b2, out, n);
}

// Round 8
// 173.767 us; speedup vs baseline: 3.3223x; 1.0209x over previous
//
#include <hip/hip_runtime.h>
#include <hip/hip_fp16.h>

#define FEAT 32
#define BIN_NODES 128
#define BIN_SHIFT 7
#define TILE_EDGES 8192   // edges per build block
#define BWAVES 16         // waves in a 1024-thread block
#define NC 8              // histogram copies in binAC
#define SRC_BITS 20
#define SRC_MASK 0xFFFFF
#define STAGE_CAP 6144    // LDS staging cap for a bin's packed edges (24 KB)

__device__ __forceinline__ int load_idx(const void* raw, int f, long long i) {
    return f ? (int)((const long long*)raw)[i] : ((const int*)raw)[i];
}

// cursor[b] = b*cap  (slot base for bin b in the slotted packed buffer)
__global__ __launch_bounds__(1024)
void initc_kernel(int* __restrict__ cursor, int nb, int cap) {
    int t = threadIdx.x;
    if (t < nb) cursor[t] = t * cap;
}

// Fused binA+binC: ONE pass over the edge list. Tile -> registers (8/thread),
// 8-copy LDS histogram of this tile, per-bin range reservation via one global
// atomicAdd per non-empty bin (order within bin nondeterministic - harmless,
// degsort re-sorts by node), scatter packed recs from registers into the
// bin's slot. rec = src | dst_local<<20.
__global__ __launch_bounds__(1024)
void binAC_kernel(const void* __restrict__ raw, int* __restrict__ cursor,
                  int* __restrict__ packed, int e, int nb) {
    extern __shared__ int lds[];   // NC*nb (hist) + nb (cur) + 1 (nz)
    int t = threadIdx.x;
    int* hist = lds;
    int* cur  = lds + NC * nb;
    int* nz   = lds + NC * nb + nb;
    for (int i = t; i < NC * nb; i += 1024) hist[i] = 0;
    if (t == 0) *nz = 0;
    __syncthreads();
    if (((const int*)raw)[2 * t + 1] != 0) *nz = 1;   // int64 detect (benign race)
    __syncthreads();
    const int f = (*nz == 0) ? 1 : 0;

    long long base = (long long)blockIdx.x * TILE_EDGES;
    int cnt = (int)min((long long)TILE_EDGES, (long long)e - base);
    int sreg[8], dreg[8];
    int* hw = hist + ((t >> 6) & (NC - 1)) * nb;   // 2 waves per copy
#pragma unroll
    for (int k = 0; k < 8; ++k) {
        int i = t + k * 1024;
        if (i < cnt) {
            sreg[k] = load_idx(raw, f, base + i);
            dreg[k] = load_idx(raw, f, (long long)e + base + i);
            atomicAdd(&hw[dreg[k] >> BIN_SHIFT], 1);
        } else {
            dreg[k] = -1;
        }
    }
    __syncthreads();
    for (int b = t; b < nb; b += 1024) {
        int s = 0;
#pragma unroll
        for (int c = 0; c < NC; ++c) s += hist[c * nb + b];
        cur[b] = s ? atomicAdd(&cursor[b], s) : 0;
    }
    __syncthreads();
#pragma unroll
    for (int k = 0; k < 8; ++k) {
        int d = dreg[k];
        if (d >= 0) {
            int pos = atomicAdd(&cur[d >> BIN_SHIFT], 1);
            packed[pos] = sreg[k] | ((d & (BIN_NODES - 1)) << SRC_BITS);
        }
    }
}

// Per-bin: 16 wave-private LDS histograms -> scan -> dis/row_meta + per-wave
// base cursors, then contention-free counting-sort into the SLOTTED recs
// buffer (bin b owns [b*cap,(b+1)*cap)) - no global scan needed; per-node
// extent goes to row_meta = {start, deg}. The bin's edges are staged in LDS
// during the count pass. FUSED layer-1: h1 = fp16(dis*(x@W1)), W1 in LDS.
__global__ __launch_bounds__(1024)
void degsort_kernel(const int* __restrict__ packed, const int* __restrict__ cursor,
                    float* __restrict__ dis, int2* __restrict__ row_meta,
                    int* __restrict__ recs, const float* __restrict__ x,
                    const float* __restrict__ W1, __half* __restrict__ h1,
                    int e, int n, int nb, int cap) {
    __shared__ int cnt[BWAVES][BIN_NODES];   // 8 KB
    __shared__ int wcur[BWAVES][BIN_NODES];  // 8 KB
    __shared__ int exc[BIN_NODES];
    __shared__ float sdis[BIN_NODES];
    __shared__ float W1l[FEAT * FEAT];       // 4 KB
    __shared__ int stage[STAGE_CAP];         // 24 KB
    int b = blockIdx.x, t = threadIdx.x;
    int w = t >> 6;
    for (int i = t; i < BWAVES * BIN_NODES; i += 1024) ((int*)cnt)[i] = 0;
    if (t < FEAT * FEAT) W1l[t] = W1[t];   // 1024 threads, 1024 elems
    __syncthreads();
    int pbase = b * cap;
    int m = cursor[b] - pbase;   // final cursor = slot base + count
    if (m <= STAGE_CAP) {
        for (int i = t; i < m; i += 1024) {
            int rec = packed[pbase + i];
            stage[i] = rec;
            atomicAdd(&cnt[w][rec >> SRC_BITS], 1);
        }
    } else {
        for (int i = t; i < m; i += 1024)
            atomicAdd(&cnt[w][packed[pbase + i] >> SRC_BITS], 1);
    }
    __syncthreads();
    if (t < BIN_NODES) {
        int s = 0;
#pragma unroll
        for (int w2 = 0; w2 < BWAVES; ++w2) s += cnt[w2][t];
        exc[t] = s;
    }
    __syncthreads();
    for (int off = 1; off < BIN_NODES; off <<= 1) {
        int v = 0;
        if (t < BIN_NODES && t >= off) v = exc[t - off];
        __syncthreads();
        if (t < BIN_NODES) exc[t] += v;
        __syncthreads();
    }
    if (t < BIN_NODES) {
        int tot = 0;
#pragma unroll
        for (int w2 = 0; w2 < BWAVES; ++w2) tot += cnt[w2][t];
        int rs = pbase + exc[t] - tot;   // inclusive -> exclusive, slot-based
        int run = rs;
#pragma unroll
        for (int w2 = 0; w2 < BWAVES; ++w2) { wcur[w2][t] = run; run += cnt[w2][t]; }
        float dv = rsqrtf((float)tot + 1.0f);
        sdis[t] = dv;
        int node = b * BIN_NODES + t;
        if (node < n) {
            dis[node] = dv;
            row_meta[node] = make_int2(rs, tot);
        }
    }
    __syncthreads();
    if (m <= STAGE_CAP) {
        for (int i = t; i < m; i += 1024) {
            int rec = stage[i];
            int pos = atomicAdd(&wcur[w][rec >> SRC_BITS], 1);
            recs[pos] = rec & SRC_MASK;
        }
    } else {
        for (int i = t; i < m; i += 1024) {
            int rec = packed[pbase + i];
            int pos = atomicAdd(&wcur[w][rec >> SRC_BITS], 1);
            recs[pos] = rec & SRC_MASK;
        }
    }
    // fused mm1: 8 threads/node, each thread holds one float4 of the x-row and
    // produces 4 output features; 8-wide shfl broadcasts the x values.
    {
        int ln = b * BIN_NODES + (t >> 3);
        if (ln < n) {
            int q = t & 7;
            float4 xv = ((const float4*)x)[(size_t)ln * 8 + q];
            float xr[4] = {xv.x, xv.y, xv.z, xv.w};
            float o[4] = {0.f, 0.f, 0.f, 0.f};
#pragma unroll
            for (int k = 0; k < FEAT; ++k) {
                float xk = __shfl(xr[k & 3], k >> 2, 8);
#pragma unroll
                for (int c = 0; c < 4; ++c)
                    o[c] = fmaf(xk, W1l[k * FEAT + q * 4 + c], o[c]);
            }
            float dn = sdis[t >> 3];
            __half2* hp = (__half2*)&h1[(size_t)ln * FEAT + q * 4];
            hp[0] = __halves2half2(__float2half(dn * o[0]), __float2half(dn * o[1]));
            hp[1] = __halves2half2(__float2half(dn * o[2]), __float2half(dn * o[3]));
        }
    }
}

// Layer-1 pull FUSED with layer-2 transform, 16 lanes/node (4 slots x 4
// feature-quads): 4 gathers in flight per lane, 2-level slot butterfly, then
// mm2 as distributed 8x8 register blocks + 2-level fb butterfly. W2 staged in
// LDS with per-k-block column rotation (bank-conflict-free). Self-row/dis/
// bias loads hoisted above the gather loop to overlap their latency.
__global__ __launch_bounds__(256, 8)
void pull_mm_kernel(const int* __restrict__ recs, const int2* __restrict__ row_meta,
                    const __half* __restrict__ h, const float* __restrict__ dis,
                    const float* __restrict__ bias, const float* __restrict__ W2,
                    __half* __restrict__ h2, int n) {
    __shared__ float Wl[FEAT * FEAT];
    int t = threadIdx.x;
    for (int i = t; i < FEAT * FEAT; i += 256) {
        int k = i >> 5, j = i & 31;
        int col = (j & 24) | ((j + 2 * (k >> 3)) & 7);   // rotate within 8-block
        Wl[k * FEAT + col] = W2[i];
    }
    __syncthreads();
    int node = blockIdx.x * 16 + (t >> 4);
    if (node >= n) return;
    int g = t & 15;
    int sub = g >> 2;   // record slot 0..3
    int fb = g & 3;     // float4 feature block (8 halves)
    int2 md = row_meta[node];
    int start = md.x, deg = md.y;
    const float4* h4 = (const float4*)h;  // 8 halves per float4, 4 per row
    // hoisted epilogue operands (latency overlaps the gather loop)
    float dn = dis[node];
    float4 hv = h4[(size_t)node * 4 + fb];   // self-loop row
    const float4* bv4 = (const float4*)bias;
    float4 b0 = bv4[fb * 2], b1 = bv4[fb * 2 + 1];
    float s0 = 0, s1 = 0, s2 = 0, s3 = 0, s4 = 0, s5 = 0, s6 = 0, s7 = 0;
    for (int r0 = 0; r0 < deg; r0 += 32) {
#pragma unroll
        for (int w = 0; w < 8; ++w) {
            int r = r0 + w * 4 + sub;
            if (r < deg) {
                int s = recs[start + r];
                float4 v = h4[(size_t)s * 4 + fb];
                const __half2* hp = (const __half2*)&v;
                float2 a = __half22float2(hp[0]);
                float2 b = __half22float2(hp[1]);
                float2 c = __half22float2(hp[2]);
                float2 d = __half22float2(hp[3]);
                s0 += a.x; s1 += a.y; s2 += b.x; s3 += b.y;
                s4 += c.x; s5 += c.y; s6 += d.x; s7 += d.y;
            }
        }
    }
    // 2-level butterfly over slots (xor 4, 8) -> all 16 lanes hold fb totals
#pragma unroll
    for (int m = 4; m <= 8; m <<= 1) {
        s0 += __shfl_xor(s0, m, 64); s1 += __shfl_xor(s1, m, 64);
        s2 += __shfl_xor(s2, m, 64); s3 += __shfl_xor(s3, m, 64);
        s4 += __shfl_xor(s4, m, 64); s5 += __shfl_xor(s5, m, 64);
        s6 += __shfl_xor(s6, m, 64); s7 += __shfl_xor(s7, m, 64);
    }
    const __half2* hp = (const __half2*)&hv;
    float2 a = __half22float2(hp[0]);
    float2 b = __half22float2(hp[1]);
    float2 c = __half22float2(hp[2]);
    float2 d = __half22float2(hp[3]);
    float o[8];
    o[0] = fmaxf(fmaf(dn, s0 + a.x, b0.x), 0.0f);
    o[1] = fmaxf(fmaf(dn, s1 + a.y, b0.y), 0.0f);
    o[2] = fmaxf(fmaf(dn, s2 + b.x, b0.z), 0.0f);
    o[3] = fmaxf(fmaf(dn, s3 + b.y, b0.w), 0.0f);
    o[4] = fmaxf(fmaf(dn, s4 + c.x, b1.x), 0.0f);
    o[5] = fmaxf(fmaf(dn, s5 + c.y, b1.y), 0.0f);
    o[6] = fmaxf(fmaf(dn, s6 + d.x, b1.z), 0.0f);
    o[7] = fmaxf(fmaf(dn, s7 + d.y, b1.w), 0.0f);
    // mm2: lane (sub,fb) computes the 8x8 block k in [8fb,8fb+8) x j in
    // [8sub,8sub+8) of relu(out1) @ W2, entirely from registers + LDS.
    float part[8] = {0.f, 0.f, 0.f, 0.f, 0.f, 0.f, 0.f, 0.f};
    const float* wrow = &Wl[(fb * 8) * FEAT + sub * 8];
#pragma unroll
    for (int cc = 0; cc < 8; ++cc) {
#pragma unroll
        for (int c2 = 0; c2 < 8; ++c2)
            part[c2] = fmaf(o[cc], wrow[cc * FEAT + ((c2 + 2 * fb) & 7)], part[c2]);
    }
    // 2-level butterfly over fb (xor 1, 2) -> full k-sum for features 8sub+c2
#pragma unroll
    for (int m = 1; m <= 2; m <<= 1) {
        part[0] += __shfl_xor(part[0], m, 64); part[1] += __shfl_xor(part[1], m, 64);
        part[2] += __shfl_xor(part[2], m, 64); part[3] += __shfl_xor(part[3], m, 64);
        part[4] += __shfl_xor(part[4], m, 64); part[5] += __shfl_xor(part[5], m, 64);
        part[6] += __shfl_xor(part[6], m, 64); part[7] += __shfl_xor(part[7], m, 64);
    }
    if (fb == 0) {
        __half2 p0 = __halves2half2(__float2half(dn * part[0]), __float2half(dn * part[1]));
        __half2 p1 = __halves2half2(__float2half(dn * part[2]), __float2half(dn * part[3]));
        __half2 p2 = __halves2half2(__float2half(dn * part[4]), __float2half(dn * part[5]));
        __half2 p3 = __halves2half2(__float2half(dn * part[6]), __float2half(dn * part[7]));
        float4 pk;
        ((__half2*)&pk)[0] = p0; ((__half2*)&pk)[1] = p1;
        ((__half2*)&pk)[2] = p2; ((__half2*)&pk)[3] = p3;
        ((float4*)h2)[(size_t)node * 4 + sub] = pk;  // features 8sub..8sub+7
    }
}

// Final pull, 16 lanes/node: out[d] = relu( dis[d]*(sum h~[s] + h~[d]) + b ).
__global__ __launch_bounds__(256, 8)
void pull_kernel(const int* __restrict__ recs, const int2* __restrict__ row_meta,
                 const __half* __restrict__ h, const float* __restrict__ dis,
                 const float* __restrict__ bias, float* __restrict__ out, int n) {
    int t = threadIdx.x;
    int node = blockIdx.x * 16 + (t >> 4);
    if (node >= n) return;
    int g = t & 15;
    int sub = g >> 2;   // record slot 0..3
    int fb = g & 3;     // float4 feature block (8 halves)
    int2 md = row_meta[node];
    int start = md.x, deg = md.y;
    const float4* h4 = (const float4*)h;  // 8 halves per float4, 4 per row
    // hoisted epilogue operands
    float dn = dis[node];
    float4 hv = h4[(size_t)node * 4 + fb];   // self-loop row
    const float4* bv4 = (const float4*)bias;
    float4 b0 = bv4[fb * 2], b1 = bv4[fb * 2 + 1];
    float s0 = 0, s1 = 0, s2 = 0, s3 = 0, s4 = 0, s5 = 0, s6 = 0, s7 = 0;
    for (int r0 = 0; r0 < deg; r0 += 32) {
#pragma unroll
        for (int w = 0; w < 8; ++w) {
            int r = r0 + w * 4 + sub;
            if (r < deg) {
                int s = recs[start + r];
                float4 v = h4[(size_t)s * 4 + fb];
                const __half2* hp = (const __half2*)&v;
                float2 a = __half22float2(hp[0]);
                float2 b = __half22float2(hp[1]);
                float2 c = __half22float2(hp[2]);
                float2 d = __half22float2(hp[3]);
                s0 += a.x; s1 += a.y; s2 += b.x; s3 += b.y;
                s4 += c.x; s5 += c.y; s6 += d.x; s7 += d.y;
            }
        }
    }
#pragma unroll
    for (int m = 4; m <= 8; m <<= 1) {
        s0 += __shfl_xor(s0, m, 64); s1 += __shfl_xor(s1, m, 64);
        s2 += __shfl_xor(s2, m, 64); s3 += __shfl_xor(s3, m, 64);
        s4 += __shfl_xor(s4, m, 64); s5 += __shfl_xor(s5, m, 64);
        s6 += __shfl_xor(s6, m, 64); s7 += __shfl_xor(s7, m, 64);
    }
    if (sub == 0) {
        const __half2* hp = (const __half2*)&hv;
        float2 a = __half22float2(hp[0]);
        float2 b = __half22float2(hp[1]);
        float2 c = __half22float2(hp[2]);
        float2 d = __half22float2(hp[3]);
        float4 o0, o1;
        o0.x = fmaxf(fmaf(dn, s0 + a.x, b0.x), 0.0f);
        o0.y = fmaxf(fmaf(dn, s1 + a.y, b0.y), 0.0f);
        o0.z = fmaxf(fmaf(dn, s2 + b.x, b0.z), 0.0f);
        o0.w = fmaxf(fmaf(dn, s3 + b.y, b0.w), 0.0f);
        o1.x = fmaxf(fmaf(dn, s4 + c.x, b1.x), 0.0f);
        o1.y = fmaxf(fmaf(dn, s5 + c.y, b1.y), 0.0f);
        o1.z = fmaxf(fmaf(dn, s6 + d.x, b1.z), 0.0f);
        o1.w = fmaxf(fmaf(dn, s7 + d.y, b1.w), 0.0f);
        ((float4*)out)[(size_t)node * 8 + fb * 2] = o0;
        ((float4*)out)[(size_t)node * 8 + fb * 2 + 1] = o1;
    }
}

extern "C" void kernel_launch(void* const* d_in, const int* in_sizes, int n_in,
                              void* d_out, int out_size, void* d_ws, size_t ws_size,
                              hipStream_t stream) {
    const float* x = (const float*)d_in[0];
    const void* eidx_raw = d_in[1];
    const float* W1 = (const float*)d_in[2];
    const float* b1 = (const float*)d_in[3];
    const float* W2 = (const float*)d_in[4];
    const float* b2 = (const float*)d_in[5];
    float* out = (float*)d_out;

    const int n = in_sizes[0] / FEAT;                    // 100000
    const int e = in_sizes[1] / 2;                       // 1600000
    const int nb = (n + BIN_NODES - 1) / BIN_NODES;      // 782
    const int nblk = (e + TILE_EDGES - 1) / TILE_EDGES;  // 196
    const int avg = (e + nb - 1) / nb;                   // ~2046
    const int cap = (avg + (avg >> 1) + 255) & ~255;     // 3072 (~22 sigma)

    // Workspace (256B-aligned). `packed` (slotted, nb*cap ints) aliases `h2`
    // (packed dead after degsort; h2 first written by pull_mm). `recs` is
    // also slotted (same geometry) - per-node extents live in row_meta.
    char* ws = (char*)d_ws;
    size_t off = 0;
    auto alloc = [&](size_t bytes) { char* p = ws + off; off = (off + bytes + 255) & ~(size_t)255; return p; };
    size_t  slot_bytes = ((size_t)nb * cap + 1024) * 4;  // +4KB slack
    int*    cursor    = (int*)   alloc((size_t)nb * 4);
    float*  dis       = (float*) alloc((size_t)n * 4);
    int2*   row_meta  = (int2*)  alloc((size_t)n * 8);
    int*    recs      = (int*)   alloc(slot_bytes);
    __half* h1        = (__half*)alloc((size_t)n * FEAT * 2);
    size_t  h2_bytes  = (size_t)n * FEAT * 2;
    __half* h2        = (__half*)alloc(slot_bytes > h2_bytes ? slot_bytes : h2_bytes);
    int*    packed    = (int*)h2;

    const size_t ldsAC = (size_t)(NC * nb + nb + 1) * 4;   // ~27.5 KB
    const int gNode = (n + 15) / 16;

    // CSR build: edge list read exactly once (binAC); no global scan.
    initc_kernel<<<1, 1024, 0, stream>>>(cursor, nb, cap);
    binAC_kernel<<<nblk, 1024, ldsAC, stream>>>(eidx_raw, cursor, packed, e, nb);
    degsort_kernel<<<nb, 1024, 0, stream>>>(packed, cursor, dis, row_meta,
                                            recs, x, W1, h1, e, n, nb, cap);

    // Layer-1 aggregate + fused layer-2 transform (-> h2)
    pull_mm_kernel<<<gNode, 256, 0, stream>>>(recs, row_meta, h1, dis, b1, W2, h2, n);
    // Layer-2 aggregate + bias + final relu
    pull_kernel<<<gNode, 256, 0, stream>>>(recs, row_meta, h2, dis, b2, out, n);
}

// Round 9
// 173.690 us; speedup vs baseline: 3.3238x; 1.0004x over previous
//
#include <hip/hip_runtime.h>
#include <hip/hip_fp16.h>

#define FEAT 32
#define BIN_NODES 128
#define BIN_SHIFT 7
#define TILE_EDGES 8192   // edges per build block
#define BWAVES 16         // waves in a 1024-thread block
#define NC 8              // histogram copies in binAC
#define SRC_BITS 20
#define SRC_MASK 0xFFFFF
#define STAGE_CAP 6144    // LDS staging cap for a bin's packed edges (24 KB)

__device__ __forceinline__ int load_idx(const void* raw, int f, long long i) {
    return f ? (int)((const long long*)raw)[i] : ((const int*)raw)[i];
}

// cursor[b] = b*cap  (slot base for bin b in the slotted packed buffer)
__global__ __launch_bounds__(1024)
void initc_kernel(int* __restrict__ cursor, int nb, int cap) {
    int t = threadIdx.x;
    if (t < nb) cursor[t] = t * cap;
}

// Fused binA+binC: ONE pass over the edge list. Tile -> registers (8/thread),
// 8-copy LDS histogram of this tile, per-bin range reservation via one global
// atomicAdd per non-empty bin (order within bin nondeterministic - harmless,
// degsort re-sorts by node), scatter packed recs from registers into the
// bin's slot. rec = src | dst_local<<20.
__global__ __launch_bounds__(1024)
void binAC_kernel(const void* __restrict__ raw, int* __restrict__ cursor,
                  int* __restrict__ packed, int e, int nb) {
    extern __shared__ int lds[];   // NC*nb (hist) + nb (cur) + 1 (nz)
    int t = threadIdx.x;
    int* hist = lds;
    int* cur  = lds + NC * nb;
    int* nz   = lds + NC * nb + nb;
    for (int i = t; i < NC * nb; i += 1024) hist[i] = 0;
    if (t == 0) *nz = 0;
    __syncthreads();
    if (((const int*)raw)[2 * t + 1] != 0) *nz = 1;   // int64 detect (benign race)
    __syncthreads();
    const int f = (*nz == 0) ? 1 : 0;

    long long base = (long long)blockIdx.x * TILE_EDGES;
    int cnt = (int)min((long long)TILE_EDGES, (long long)e - base);
    int sreg[8], dreg[8];
    int* hw = hist + ((t >> 6) & (NC - 1)) * nb;   // 2 waves per copy
#pragma unroll
    for (int k = 0; k < 8; ++k) {
        int i = t + k * 1024;
        if (i < cnt) {
            sreg[k] = load_idx(raw, f, base + i);
            dreg[k] = load_idx(raw, f, (long long)e + base + i);
            atomicAdd(&hw[dreg[k] >> BIN_SHIFT], 1);
        } else {
            dreg[k] = -1;
        }
    }
    __syncthreads();
    for (int b = t; b < nb; b += 1024) {
        int s = 0;
#pragma unroll
        for (int c = 0; c < NC; ++c) s += hist[c * nb + b];
        cur[b] = s ? atomicAdd(&cursor[b], s) : 0;
    }
    __syncthreads();
#pragma unroll
    for (int k = 0; k < 8; ++k) {
        int d = dreg[k];
        if (d >= 0) {
            int pos = atomicAdd(&cur[d >> BIN_SHIFT], 1);
            packed[pos] = sreg[k] | ((d & (BIN_NODES - 1)) << SRC_BITS);
        }
    }
}

// Per-bin: 16 wave-private LDS histograms -> scan -> dis/row_meta + per-wave
// base cursors, then contention-free counting-sort into the SLOTTED recs
// buffer (bin b owns [b*cap,(b+1)*cap)) - no global scan needed; per-node
// extent goes to row_meta = {start, deg}. The bin's edges are staged in LDS
// during the count pass. FUSED layer-1: h1 = fp16(dis*(x@W1)), W1 in LDS.
__global__ __launch_bounds__(1024)
void degsort_kernel(const int* __restrict__ packed, const int* __restrict__ cursor,
                    float* __restrict__ dis, int2* __restrict__ row_meta,
                    int* __restrict__ recs, const float* __restrict__ x,
                    const float* __restrict__ W1, __half* __restrict__ h1,
                    int e, int n, int nb, int cap) {
    __shared__ int cnt[BWAVES][BIN_NODES];   // 8 KB
    __shared__ int wcur[BWAVES][BIN_NODES];  // 8 KB
    __shared__ int exc[BIN_NODES];
    __shared__ float sdis[BIN_NODES];
    __shared__ float W1l[FEAT * FEAT];       // 4 KB
    __shared__ int stage[STAGE_CAP];         // 24 KB
    int b = blockIdx.x, t = threadIdx.x;
    int w = t >> 6;
    for (int i = t; i < BWAVES * BIN_NODES; i += 1024) ((int*)cnt)[i] = 0;
    if (t < FEAT * FEAT) W1l[t] = W1[t];   // 1024 threads, 1024 elems
    __syncthreads();
    int pbase = b * cap;
    int m = cursor[b] - pbase;   // final cursor = slot base + count
    if (m <= STAGE_CAP) {
        for (int i = t; i < m; i += 1024) {
            int rec = packed[pbase + i];
            stage[i] = rec;
            atomicAdd(&cnt[w][rec >> SRC_BITS], 1);
        }
    } else {
        for (int i = t; i < m; i += 1024)
            atomicAdd(&cnt[w][packed[pbase + i] >> SRC_BITS], 1);
    }
    __syncthreads();
    if (t < BIN_NODES) {
        int s = 0;
#pragma unroll
        for (int w2 = 0; w2 < BWAVES; ++w2) s += cnt[w2][t];
        exc[t] = s;
    }
    __syncthreads();
    for (int off = 1; off < BIN_NODES; off <<= 1) {
        int v = 0;
        if (t < BIN_NODES && t >= off) v = exc[t - off];
        __syncthreads();
        if (t < BIN_NODES) exc[t] += v;
        __syncthreads();
    }
    if (t < BIN_NODES) {
        int tot = 0;
#pragma unroll
        for (int w2 = 0; w2 < BWAVES; ++w2) tot += cnt[w2][t];
        int rs = pbase + exc[t] - tot;   // inclusive -> exclusive, slot-based
        int run = rs;
#pragma unroll
        for (int w2 = 0; w2 < BWAVES; ++w2) { wcur[w2][t] = run; run += cnt[w2][t]; }
        float dv = rsqrtf((float)tot + 1.0f);
        sdis[t] = dv;
        int node = b * BIN_NODES + t;
        if (node < n) {
            dis[node] = dv;
            row_meta[node] = make_int2(rs, tot);
        }
    }
    __syncthreads();
    if (m <= STAGE_CAP) {
        for (int i = t; i < m; i += 1024) {
            int rec = stage[i];
            int pos = atomicAdd(&wcur[w][rec >> SRC_BITS], 1);
            recs[pos] = rec & SRC_MASK;
        }
    } else {
        for (int i = t; i < m; i += 1024) {
            int rec = packed[pbase + i];
            int pos = atomicAdd(&wcur[w][rec >> SRC_BITS], 1);
            recs[pos] = rec & SRC_MASK;
        }
    }
    // fused mm1: 8 threads/node, each thread holds one float4 of the x-row and
    // produces 4 output features; 8-wide shfl broadcasts the x values.
    {
        int ln = b * BIN_NODES + (t >> 3);
        if (ln < n) {
            int q = t & 7;
            float4 xv = ((const float4*)x)[(size_t)ln * 8 + q];
            float xr[4] = {xv.x, xv.y, xv.z, xv.w};
            float o[4] = {0.f, 0.f, 0.f, 0.f};
#pragma unroll
            for (int k = 0; k < FEAT; ++k) {
                float xk = __shfl(xr[k & 3], k >> 2, 8);
#pragma unroll
                for (int c = 0; c < 4; ++c)
                    o[c] = fmaf(xk, W1l[k * FEAT + q * 4 + c], o[c]);
            }
            float dn = sdis[t >> 3];
            __half2* hp = (__half2*)&h1[(size_t)ln * FEAT + q * 4];
            hp[0] = __halves2half2(__float2half(dn * o[0]), __float2half(dn * o[1]));
            hp[1] = __halves2half2(__float2half(dn * o[2]), __float2half(dn * o[3]));
        }
    }
}

// Layer-1 pull FUSED with layer-2 transform, 16 lanes/node (4 slots x 4
// feature-quads): 4 gathers in flight per lane, 2-level slot butterfly, then
// mm2 as distributed 8x8 register blocks + 2-level fb butterfly. W2 staged in
// LDS with per-k-block column rotation (bank-conflict-free). Self-row/dis/
// bias loads hoisted above the gather loop to overlap their latency.
__global__ __launch_bounds__(256, 8)
void pull_mm_kernel(const int* __restrict__ recs, const int2* __restrict__ row_meta,
                    const __half* __restrict__ h, const float* __restrict__ dis,
                    const float* __restrict__ bias, const float* __restrict__ W2,
                    __half* __restrict__ h2, int n) {
    __shared__ float Wl[FEAT * FEAT];
    int t = threadIdx.x;
    for (int i = t; i < FEAT * FEAT; i += 256) {
        int k = i >> 5, j = i & 31;
        int col = (j & 24) | ((j + 2 * (k >> 3)) & 7);   // rotate within 8-block
        Wl[k * FEAT + col] = W2[i];
    }
    __syncthreads();
    int node = blockIdx.x * 16 + (t >> 4);
    if (node >= n) return;
    int g = t & 15;
    int sub = g >> 2;   // record slot 0..3
    int fb = g & 3;     // float4 feature block (8 halves)
    int2 md = row_meta[node];
    int start = md.x, deg = md.y;
    const float4* h4 = (const float4*)h;  // 8 halves per float4, 4 per row
    // hoisted epilogue operands (latency overlaps the gather loop)
    float dn = dis[node];
    float4 hv = h4[(size_t)node * 4 + fb];   // self-loop row
    const float4* bv4 = (const float4*)bias;
    float4 b0 = bv4[fb * 2], b1 = bv4[fb * 2 + 1];
    float s0 = 0, s1 = 0, s2 = 0, s3 = 0, s4 = 0, s5 = 0, s6 = 0, s7 = 0;
    for (int r0 = 0; r0 < deg; r0 += 32) {
#pragma unroll
        for (int w = 0; w < 8; ++w) {
            int r = r0 + w * 4 + sub;
            if (r < deg) {
                int s = recs[start + r];
                float4 v = h4[(size_t)s * 4 + fb];
                const __half2* hp = (const __half2*)&v;
                float2 a = __half22float2(hp[0]);
                float2 b = __half22float2(hp[1]);
                float2 c = __half22float2(hp[2]);
                float2 d = __half22float2(hp[3]);
                s0 += a.x; s1 += a.y; s2 += b.x; s3 += b.y;
                s4 += c.x; s5 += c.y; s6 += d.x; s7 += d.y;
            }
        }
    }
    // 2-level butterfly over slots (xor 4, 8) -> all 16 lanes hold fb totals
#pragma unroll
    for (int m = 4; m <= 8; m <<= 1) {
        s0 += __shfl_xor(s0, m, 64); s1 += __shfl_xor(s1, m, 64);
        s2 += __shfl_xor(s2, m, 64); s3 += __shfl_xor(s3, m, 64);
        s4 += __shfl_xor(s4, m, 64); s5 += __shfl_xor(s5, m, 64);
        s6 += __shfl_xor(s6, m, 64); s7 += __shfl_xor(s7, m, 64);
    }
    const __half2* hp = (const __half2*)&hv;
    float2 a = __half22float2(hp[0]);
    float2 b = __half22float2(hp[1]);
    float2 c = __half22float2(hp[2]);
    float2 d = __half22float2(hp[3]);
    float o[8];
    o[0] = fmaxf(fmaf(dn, s0 + a.x, b0.x), 0.0f);
    o[1] = fmaxf(fmaf(dn, s1 + a.y, b0.y), 0.0f);
    o[2] = fmaxf(fmaf(dn, s2 + b.x, b0.z), 0.0f);
    o[3] = fmaxf(fmaf(dn, s3 + b.y, b0.w), 0.0f);
    o[4] = fmaxf(fmaf(dn, s4 + c.x, b1.x), 0.0f);
    o[5] = fmaxf(fmaf(dn, s5 + c.y, b1.y), 0.0f);
    o[6] = fmaxf(fmaf(dn, s6 + d.x, b1.z), 0.0f);
    o[7] = fmaxf(fmaf(dn, s7 + d.y, b1.w), 0.0f);
    // mm2: lane (sub,fb) computes the 8x8 block k in [8fb,8fb+8) x j in
    // [8sub,8sub+8) of relu(out1) @ W2, entirely from registers + LDS.
    float part[8] = {0.f, 0.f, 0.f, 0.f, 0.f, 0.f, 0.f, 0.f};
    const float* wrow = &Wl[(fb * 8) * FEAT + sub * 8];
#pragma unroll
    for (int cc = 0; cc < 8; ++cc) {
#pragma unroll
        for (int c2 = 0; c2 < 8; ++c2)
            part[c2] = fmaf(o[cc], wrow[cc * FEAT + ((c2 + 2 * fb) & 7)], part[c2]);
    }
    // 2-level butterfly over fb (xor 1, 2) -> full k-sum for features 8sub+c2
#pragma unroll
    for (int m = 1; m <= 2; m <<= 1) {
        part[0] += __shfl_xor(part[0], m, 64); part[1] += __shfl_xor(part[1], m, 64);
        part[2] += __shfl_xor(part[2], m, 64); part[3] += __shfl_xor(part[3], m, 64);
        part[4] += __shfl_xor(part[4], m, 64); part[5] += __shfl_xor(part[5], m, 64);
        part[6] += __shfl_xor(part[6], m, 64); part[7] += __shfl_xor(part[7], m, 64);
    }
    if (fb == 0) {
        __half2 p0 = __halves2half2(__float2half(dn * part[0]), __float2half(dn * part[1]));
        __half2 p1 = __halves2half2(__float2half(dn * part[2]), __float2half(dn * part[3]));
        __half2 p2 = __halves2half2(__float2half(dn * part[4]), __float2half(dn * part[5]));
        __half2 p3 = __halves2half2(__float2half(dn * part[6]), __float2half(dn * part[7]));
        float4 pk;
        ((__half2*)&pk)[0] = p0; ((__half2*)&pk)[1] = p1;
        ((__half2*)&pk)[2] = p2; ((__half2*)&pk)[3] = p3;
        ((float4*)h2)[(size_t)node * 4 + sub] = pk;  // features 8sub..8sub+7
    }
}

// Final pull, 8 lanes/node (2 slots x 4 feature-quads): window = 16 records
// ~ deg, so all 8 unrolled load slots are useful -> 8 gathers in flight per
// lane (2x the 16-lane layout). 1-level slot butterfly.
__global__ __launch_bounds__(256, 8)
void pull_kernel(const int* __restrict__ recs, const int2* __restrict__ row_meta,
                 const __half* __restrict__ h, const float* __restrict__ dis,
                 const float* __restrict__ bias, float* __restrict__ out, int n) {
    int t = threadIdx.x;
    int node = blockIdx.x * 32 + (t >> 3);
    if (node >= n) return;
    int g = t & 7;
    int sub = g >> 2;   // record slot 0..1
    int fb = g & 3;     // float4 feature block (8 halves)
    int2 md = row_meta[node];
    int start = md.x, deg = md.y;
    const float4* h4 = (const float4*)h;  // 8 halves per float4, 4 per row
    // hoisted epilogue operands
    float dn = dis[node];
    float4 hv = h4[(size_t)node * 4 + fb];   // self-loop row
    const float4* bv4 = (const float4*)bias;
    float4 b0 = bv4[fb * 2], b1 = bv4[fb * 2 + 1];
    float s0 = 0, s1 = 0, s2 = 0, s3 = 0, s4 = 0, s5 = 0, s6 = 0, s7 = 0;
    for (int r0 = 0; r0 < deg; r0 += 16) {
#pragma unroll
        for (int w = 0; w < 8; ++w) {
            int r = r0 + w * 2 + sub;
            if (r < deg) {
                int s = recs[start + r];
                float4 v = h4[(size_t)s * 4 + fb];
                const __half2* hp = (const __half2*)&v;
                float2 a = __half22float2(hp[0]);
                float2 b = __half22float2(hp[1]);
                float2 c = __half22float2(hp[2]);
                float2 d = __half22float2(hp[3]);
                s0 += a.x; s1 += a.y; s2 += b.x; s3 += b.y;
                s4 += c.x; s5 += c.y; s6 += d.x; s7 += d.y;
            }
        }
    }
    // 1-level butterfly over slots (xor 4)
    s0 += __shfl_xor(s0, 4, 64); s1 += __shfl_xor(s1, 4, 64);
    s2 += __shfl_xor(s2, 4, 64); s3 += __shfl_xor(s3, 4, 64);
    s4 += __shfl_xor(s4, 4, 64); s5 += __shfl_xor(s5, 4, 64);
    s6 += __shfl_xor(s6, 4, 64); s7 += __shfl_xor(s7, 4, 64);
    if (sub == 0) {
        const __half2* hp = (const __half2*)&hv;
        float2 a = __half22float2(hp[0]);
        float2 b = __half22float2(hp[1]);
        float2 c = __half22float2(hp[2]);
        float2 d = __half22float2(hp[3]);
        float4 o0, o1;
        o0.x = fmaxf(fmaf(dn, s0 + a.x, b0.x), 0.0f);
        o0.y = fmaxf(fmaf(dn, s1 + a.y, b0.y), 0.0f);
        o0.z = fmaxf(fmaf(dn, s2 + b.x, b0.z), 0.0f);
        o0.w = fmaxf(fmaf(dn, s3 + b.y, b0.w), 0.0f);
        o1.x = fmaxf(fmaf(dn, s4 + c.x, b1.x), 0.0f);
        o1.y = fmaxf(fmaf(dn, s5 + c.y, b1.y), 0.0f);
        o1.z = fmaxf(fmaf(dn, s6 + d.x, b1.z), 0.0f);
        o1.w = fmaxf(fmaf(dn, s7 + d.y, b1.w), 0.0f);
        ((float4*)out)[(size_t)node * 8 + fb * 2] = o0;
        ((float4*)out)[(size_t)node * 8 + fb * 2 + 1] = o1;
    }
}

extern "C" void kernel_launch(void* const* d_in, const int* in_sizes, int n_in,
                              void* d_out, int out_size, void* d_ws, size_t ws_size,
                              hipStream_t stream) {
    const float* x = (const float*)d_in[0];
    const void* eidx_raw = d_in[1];
    const float* W1 = (const float*)d_in[2];
    const float* b1 = (const float*)d_in[3];
    const float* W2 = (const float*)d_in[4];
    const float* b2 = (const float*)d_in[5];
    float* out = (float*)d_out;

    const int n = in_sizes[0] / FEAT;                    // 100000
    const int e = in_sizes[1] / 2;                       // 1600000
    const int nb = (n + BIN_NODES - 1) / BIN_NODES;      // 782
    const int nblk = (e + TILE_EDGES - 1) / TILE_EDGES;  // 196
    const int avg = (e + nb - 1) / nb;                   // ~2046
    const int cap = (avg + (avg >> 1) + 255) & ~255;     // 3072 (~22 sigma)

    // Workspace (256B-aligned). `packed` (slotted, nb*cap ints) aliases `h2`
    // (packed dead after degsort; h2 first written by pull_mm). `recs` is
    // also slotted (same geometry) - per-node extents live in row_meta.
    char* ws = (char*)d_ws;
    size_t off = 0;
    auto alloc = [&](size_t bytes) { char* p = ws + off; off = (off + bytes + 255) & ~(size_t)255; return p; };
    size_t  slot_bytes = ((size_t)nb * cap + 1024) * 4;  // +4KB slack
    int*    cursor    = (int*)   alloc((size_t)nb * 4);
    float*  dis       = (float*) alloc((size_t)n * 4);
    int2*   row_meta  = (int2*)  alloc((size_t)n * 8);
    int*    recs      = (int*)   alloc(slot_bytes);
    __half* h1        = (__half*)alloc((size_t)n * FEAT * 2);
    size_t  h2_bytes  = (size_t)n * FEAT * 2;
    __half* h2        = (__half*)alloc(slot_bytes > h2_bytes ? slot_bytes : h2_bytes);
    int*    packed    = (int*)h2;

    const size_t ldsAC = (size_t)(NC * nb + nb + 1) * 4;   // ~27.5 KB
    const int gNode16 = (n + 15) / 16;
    const int gNode32 = (n + 31) / 32;

    // CSR build: edge list read exactly once (binAC); no global scan.
    initc_kernel<<<1, 1024, 0, stream>>>(cursor, nb, cap);
    binAC_kernel<<<nblk, 1024, ldsAC, stream>>>(eidx_raw, cursor, packed, e, nb);
    degsort_kernel<<<nb, 1024, 0, stream>>>(packed, cursor, dis, row_meta,
                                            recs, x, W1, h1, e, n, nb, cap);

    // Layer-1 aggregate + fused layer-2 transform (-> h2)
    pull_mm_kernel<<<gNode16, 256, 0, stream>>>(recs, row_meta, h1, dis, b1, W2, h2, n);
    // Layer-2 aggregate + bias + final relu
    pull_kernel<<<gNode32, 256, 0, stream>>>(recs, row_meta, h2, dis, b2, out, n);
}